// Round 1
// baseline (15268.275 us; speedup 1.0000x reference)
//
#include <hip/hip_runtime.h>
#include <math.h>

#define DD 768
#define HH 12
#define DHH 64
#define NLAYER 12
#define MFF 3072
#define VV 32000
#define BB 8
#define NN 512
#define TT (BB*NN)

// ---------- block-wide sum reduction of two values (256 threads = 4 waves) ----------
__device__ __forceinline__ void blockReduce2(float& a, float& b, float* sh) {
#pragma unroll
  for (int off = 32; off > 0; off >>= 1) {
    a += __shfl_down(a, off, 64);
    b += __shfl_down(b, off, 64);
  }
  int lane = threadIdx.x & 63;
  int w = threadIdx.x >> 6;
  if (lane == 0) { sh[2*w] = a; sh[2*w+1] = b; }
  __syncthreads();
  a = sh[0] + sh[2] + sh[4] + sh[6];
  b = sh[1] + sh[3] + sh[5] + sh[7];
}

// ---------- embedding gather + sinusoid PE + LayerNorm ----------
__global__ __launch_bounds__(256) void k_embed_ln(const float* __restrict__ emb,
    const float* __restrict__ g, const float* __restrict__ bb,
    const int* __restrict__ x, float* __restrict__ out) {
  __shared__ float sh[8];
  int tok = blockIdx.x;
  int n = tok & (NN - 1);
  int t = x[tok];
  const float* row = emb + (size_t)t * DD;
  float v[3]; float s = 0.f, ss = 0.f;
#pragma unroll
  for (int i = 0; i < 3; ++i) {
    int d = threadIdx.x + 256 * i;
    int pair = d >> 1;
    float div = expf((float)(2 * pair) * (-9.210340371976184f / (float)DD));
    float ang = (float)n * div;
    float pe = (d & 1) ? cosf(ang) : sinf(ang);
    float val = row[d] + pe;
    v[i] = val; s += val; ss += val * val;
  }
  blockReduce2(s, ss, sh);
  float mu = s * (1.f / DD);
  float var = ss * (1.f / DD) - mu * mu;
  float rs = rsqrtf(var + 1e-5f);
#pragma unroll
  for (int i = 0; i < 3; ++i) {
    int d = threadIdx.x + 256 * i;
    out[(size_t)tok * DD + d] = (v[i] - mu) * rs * g[d] + bb[d];
  }
}

// ---------- LayerNorm of (in0 [+ in1]) ----------
__global__ __launch_bounds__(256) void k_ln(const float* __restrict__ in0,
    const float* __restrict__ in1, const float* __restrict__ g,
    const float* __restrict__ bb, float* __restrict__ out) {
  __shared__ float sh[8];
  int tok = blockIdx.x;
  float v[3]; float s = 0.f, ss = 0.f;
#pragma unroll
  for (int i = 0; i < 3; ++i) {
    int d = threadIdx.x + 256 * i;
    float val = in0[(size_t)tok * DD + d];
    if (in1) val += in1[(size_t)tok * DD + d];
    v[i] = val; s += val; ss += val * val;
  }
  blockReduce2(s, ss, sh);
  float mu = s * (1.f / DD);
  float var = ss * (1.f / DD) - mu * mu;
  float rs = rsqrtf(var + 1e-5f);
#pragma unroll
  for (int i = 0; i < 3; ++i) {
    int d = threadIdx.x + 256 * i;
    out[(size_t)tok * DD + d] = (v[i] - mu) * rs * g[d] + bb[d];
  }
}

// ---------- RoPE applied in-place to q,k parts of qkv (first 32 dims/head) ----------
__global__ __launch_bounds__(384) void k_rope(float* __restrict__ qkv) {
  int tok = blockIdx.x;
  int n = tok & (NN - 1);
  int tid = threadIdx.x;
  int qk = tid / 192;            // 0 = q, 1 = k
  int rem = tid - qk * 192;
  int head = rem >> 4;
  int i = rem & 15;              // rotation pair index
  size_t base = (size_t)tok * (3 * DD) + (size_t)qk * DD + head * DHH + 2 * i;
  float inv = expf(-0.57564627324851148f * (float)i);  // 10000^(-2i/32)
  float ang = (float)n * inv;
  float c = cosf(ang), sn = sinf(ang);
  float x0 = qkv[base], x1 = qkv[base + 1];
  qkv[base]     = x0 * c - x1 * sn;
  qkv[base + 1] = x1 * c + x0 * sn;
}

// ---------- flash-style attention: one block = 32 query rows of one (b,h) ----------
__global__ __launch_bounds__(256) void k_attn(const float* __restrict__ qkv,
    const int* __restrict__ x, float* __restrict__ out) {
  __shared__ float qs[32][68];
  __shared__ float Ks[64][68];
  __shared__ float Vs[64][68];
  __shared__ float ps[32][65];
  __shared__ float maskv[64];
  int blk = blockIdx.x;
  int rb = blk & 15;
  int hh = (blk >> 4) % HH;
  int b = blk / (16 * HH);
  int i0 = rb * 32;
  int tid = threadIdx.x;
  int r = tid >> 3;        // query row 0..31 (8 lanes per row)
  int l8 = tid & 7;        // lane within row -> owns dims l8*8..l8*8+7, keys j%8==l8
  {
    int c8 = l8 * 8;
    const float* qp = qkv + (size_t)(b * NN + i0 + r) * (3 * DD) + hh * DHH + c8;
    *(float4*)&qs[r][c8] = *(const float4*)qp;
    *(float4*)&qs[r][c8 + 4] = *(const float4*)(qp + 4);
  }
  float m_run = -INFINITY, l_run = 0.f;
  float o[8] = {0.f,0.f,0.f,0.f,0.f,0.f,0.f,0.f};
  int kr = tid >> 2;             // key row for staging
  int kc = (tid & 3) * 16;
  for (int kt = 0; kt < NN; kt += 64) {
    __syncthreads();   // prev iter consumers done (and qs visible on iter 0)
    {
      const float* kp = qkv + (size_t)(b * NN + kt + kr) * (3 * DD) + DD + hh * DHH + kc;
      const float* vp = kp + DD;
#pragma unroll
      for (int q4 = 0; q4 < 4; ++q4) {
        *(float4*)&Ks[kr][kc + 4 * q4] = *(const float4*)(kp + 4 * q4);
        *(float4*)&Vs[kr][kc + 4 * q4] = *(const float4*)(vp + 4 * q4);
      }
    }
    if (tid < 64) maskv[tid] = (x[b * NN + kt + tid] == 0) ? 1.f : 0.f;
    __syncthreads();
    float sv[8];
#pragma unroll
    for (int jj = 0; jj < 8; ++jj) {
      int j = jj * 8 + l8;
      float4 acc = make_float4(0.f, 0.f, 0.f, 0.f);
#pragma unroll
      for (int dq = 0; dq < 16; ++dq) {
        float4 kq = *(const float4*)&Ks[j][4 * dq];
        float4 qq = *(const float4*)&qs[r][4 * dq];
        acc.x = fmaf(kq.x, qq.x, acc.x);
        acc.y = fmaf(kq.y, qq.y, acc.y);
        acc.z = fmaf(kq.z, qq.z, acc.z);
        acc.w = fmaf(kq.w, qq.w, acc.w);
      }
      float sd = ((acc.x + acc.y) + (acc.z + acc.w)) * 0.125f;
      if (maskv[j] != 0.f) sd = 1e-9f;   // pad-mask fills the VALUE (per reference)
      sv[jj] = sd;
    }
    float tm = sv[0];
#pragma unroll
    for (int jj = 1; jj < 8; ++jj) tm = fmaxf(tm, sv[jj]);
    tm = fmaxf(tm, __shfl_xor(tm, 1, 64));
    tm = fmaxf(tm, __shfl_xor(tm, 2, 64));
    tm = fmaxf(tm, __shfl_xor(tm, 4, 64));
    float m_new = fmaxf(m_run, tm);
    float fs = expf(m_run - m_new);      // exp(-inf)=0 handles first tile
    float tsum = 0.f;
#pragma unroll
    for (int jj = 0; jj < 8; ++jj) {
      float p = expf(sv[jj] - m_new);
      ps[r][jj * 8 + l8] = p;
      tsum += p;
    }
    tsum += __shfl_xor(tsum, 1, 64);
    tsum += __shfl_xor(tsum, 2, 64);
    tsum += __shfl_xor(tsum, 4, 64);
    l_run = l_run * fs + tsum;
    m_run = m_new;
#pragma unroll
    for (int dd = 0; dd < 8; ++dd) o[dd] *= fs;
    __syncthreads();
#pragma unroll 8
    for (int j = 0; j < 64; ++j) {
      float p = ps[r][j];
      float4 v0 = *(const float4*)&Vs[j][l8 * 8];
      float4 v1 = *(const float4*)&Vs[j][l8 * 8 + 4];
      o[0] = fmaf(p, v0.x, o[0]);
      o[1] = fmaf(p, v0.y, o[1]);
      o[2] = fmaf(p, v0.z, o[2]);
      o[3] = fmaf(p, v0.w, o[3]);
      o[4] = fmaf(p, v1.x, o[4]);
      o[5] = fmaf(p, v1.y, o[5]);
      o[6] = fmaf(p, v1.z, o[6]);
      o[7] = fmaf(p, v1.w, o[7]);
    }
  }
  float invl = 1.f / l_run;
  float* op = out + (size_t)(b * NN + i0 + r) * DD + hh * DHH + l8 * 8;
  *(float4*)op = make_float4(o[0]*invl, o[1]*invl, o[2]*invl, o[3]*invl);
  *(float4*)(op + 4) = make_float4(o[4]*invl, o[5]*invl, o[6]*invl, o[7]*invl);
}

// ---------- fp32 SGEMM: C[T x Nc] = A[T x K] @ W[K x Nc] (+bias)(+gelu) ----------
// tile 128x64, BK=16, 256 threads, 4x8 micro-tile
template<int ACT>
__global__ __launch_bounds__(256) void k_gemm(const float* __restrict__ A,
    const float* __restrict__ W, const float* __restrict__ bias,
    float* __restrict__ C, int K, int Nc) {
  __shared__ float As[16][128];
  __shared__ float Bs[16][64];
  int tid = threadIdx.x;
  int bm = blockIdx.y * 128;
  int bn = blockIdx.x * 64;
  int tmi = tid & 31;        // 32 row-groups of 4
  int tni = tid >> 5;        // 8 col-groups of 8
  int arow = tid >> 2;       // A staging: rows arow, arow+64
  int akq = (tid & 3) * 4;   // k-quad
  int bn4 = (tid & 15) * 4;
  int bkb = tid >> 4;
  const float* pA0 = A + (size_t)(bm + arow) * K + akq;
  const float* pA1 = A + (size_t)(bm + arow + 64) * K + akq;
  const float* pB  = W + (size_t)bkb * Nc + bn + bn4;
  float acc[4][8];
#pragma unroll
  for (int i = 0; i < 4; ++i)
#pragma unroll
    for (int j = 0; j < 8; ++j) acc[i][j] = 0.f;
  for (int k0 = 0; k0 < K; k0 += 16) {
    float4 a0 = *(const float4*)pA0;
    float4 a1 = *(const float4*)pA1;
    float4 b0 = *(const float4*)pB;
    __syncthreads();
    As[akq + 0][arow] = a0.x; As[akq + 1][arow] = a0.y;
    As[akq + 2][arow] = a0.z; As[akq + 3][arow] = a0.w;
    As[akq + 0][arow + 64] = a1.x; As[akq + 1][arow + 64] = a1.y;
    As[akq + 2][arow + 64] = a1.z; As[akq + 3][arow + 64] = a1.w;
    *(float4*)&Bs[bkb][bn4] = b0;
    __syncthreads();
#pragma unroll
    for (int kk = 0; kk < 16; ++kk) {
      float4 av  = *(const float4*)&As[kk][tmi * 4];
      float4 bv0 = *(const float4*)&Bs[kk][tni * 8];
      float4 bv1 = *(const float4*)&Bs[kk][tni * 8 + 4];
      float am[4] = {av.x, av.y, av.z, av.w};
      float bw[8] = {bv0.x, bv0.y, bv0.z, bv0.w, bv1.x, bv1.y, bv1.z, bv1.w};
#pragma unroll
      for (int mi = 0; mi < 4; ++mi)
#pragma unroll
        for (int nj = 0; nj < 8; ++nj)
          acc[mi][nj] = fmaf(am[mi], bw[nj], acc[mi][nj]);
    }
    pA0 += 16; pA1 += 16; pB += (size_t)16 * Nc;
  }
#pragma unroll
  for (int mi = 0; mi < 4; ++mi) {
    int rowv = bm + tmi * 4 + mi;
    float* cp = C + (size_t)rowv * Nc + bn + tni * 8;
    float vals[8];
#pragma unroll
    for (int nj = 0; nj < 8; ++nj) {
      float vv = acc[mi][nj];
      if (bias) vv += bias[bn + tni * 8 + nj];
      if (ACT == 1) vv = 0.5f * vv * (1.f + erff(vv * 0.70710678118654752f));
      vals[nj] = vv;
    }
    *(float4*)cp = make_float4(vals[0], vals[1], vals[2], vals[3]);
    *(float4*)(cp + 4) = make_float4(vals[4], vals[5], vals[6], vals[7]);
  }
}

// ---------- copy h[:,0,:] to second output ----------
__global__ void k_copyh0(const float* __restrict__ h, float* __restrict__ o2) {
  int i = blockIdx.x * 256 + threadIdx.x;
  if (i < BB * DD) {
    int b = i / DD, d = i - b * DD;
    o2[i] = h[(size_t)(b * NN) * DD + d];
  }
}

extern "C" void kernel_launch(void* const* d_in, const int* in_sizes, int n_in,
                              void* d_out, int out_size, void* d_ws, size_t ws_size,
                              hipStream_t stream) {
  const float* tok_emb = (const float*)d_in[0];
  const float* emb_g  = (const float*)d_in[1];
  const float* emb_b  = (const float*)d_in[2];
  const float* n1_g   = (const float*)d_in[3];
  const float* n1_b   = (const float*)d_in[4];
  const float* n2_g   = (const float*)d_in[5];
  const float* n2_b   = (const float*)d_in[6];
  const float* qkv_w  = (const float*)d_in[7];
  const float* out_w  = (const float*)d_in[8];
  const float* ff_g   = (const float*)d_in[9];
  const float* ff_b   = (const float*)d_in[10];
  const float* ff_w1  = (const float*)d_in[11];
  const float* ff_b1  = (const float*)d_in[12];
  const float* ff_w2  = (const float*)d_in[13];
  const float* ff_b2  = (const float*)d_in[14];
  const float* h_w1   = (const float*)d_in[15];
  const float* h_b1   = (const float*)d_in[16];
  const float* h_g    = (const float*)d_in[17];
  const float* h_b    = (const float*)d_in[18];
  const float* h_w2   = (const float*)d_in[19];
  const float* h_b2   = (const float*)d_in[20];
  const int*   xi     = (const int*)d_in[21];
  float* outp = (float*)d_out;

  float* h  = (float*)d_ws;                   // TT*DD
  float* t1 = h  + (size_t)TT * DD;           // TT*3DD  (qkv / f2 / g1)
  float* t2 = t1 + (size_t)TT * 3 * DD;       // TT*MFF  (attn out / f1)
  float* t3 = t2 + (size_t)TT * MFF;          // TT*DD   (ln tmp / head)

  k_embed_ln<<<TT, 256, 0, stream>>>(tok_emb, emb_g, emb_b, xi, h);
  for (int l = 0; l < NLAYER; ++l) {
    k_gemm<0><<<dim3(3 * DD / 64, TT / 128), 256, 0, stream>>>(
        h, qkv_w + (size_t)l * DD * 3 * DD, nullptr, t1, DD, 3 * DD);
    k_rope<<<TT, 384, 0, stream>>>(t1);
    k_attn<<<BB * HH * (NN / 32), 256, 0, stream>>>(t1, xi, t2);
    k_gemm<0><<<dim3(DD / 64, TT / 128), 256, 0, stream>>>(
        t2, out_w + (size_t)l * DD * DD, nullptr, t3, DD, DD);
    k_ln<<<TT, 256, 0, stream>>>(t3, h, n1_g, n1_b, h);
    k_ln<<<TT, 256, 0, stream>>>(h, nullptr, ff_g + (size_t)l * DD, ff_b + (size_t)l * DD, t3);
    k_gemm<1><<<dim3(MFF / 64, TT / 128), 256, 0, stream>>>(
        t3, ff_w1 + (size_t)l * DD * MFF, ff_b1 + (size_t)l * MFF, t2, DD, MFF);
    k_gemm<0><<<dim3(DD / 64, TT / 128), 256, 0, stream>>>(
        t2, ff_w2 + (size_t)l * MFF * DD, ff_b2 + (size_t)l * DD, t1, MFF, DD);
    k_ln<<<TT, 256, 0, stream>>>(t1, h, n2_g, n2_b, h);
  }
  k_gemm<1><<<dim3(DD / 64, TT / 128), 256, 0, stream>>>(h, h_w1, h_b1, t1, DD, DD);
  k_ln<<<TT, 256, 0, stream>>>(t1, nullptr, h_g, h_b, t3);
  k_gemm<0><<<dim3(VV / 64, TT / 128), 256, 0, stream>>>(t3, h_w2, h_b2, outp, DD, VV);
  k_copyh0<<<(BB * DD + 255) / 256, 256, 0, stream>>>(h, outp + (size_t)TT * VV);
}

// Round 2
// 7589.774 us; speedup vs baseline: 2.0117x; 2.0117x over previous
//
#include <hip/hip_runtime.h>
#include <math.h>

#define DD 768
#define HH 12
#define DHH 64
#define NLAYER 12
#define MFF 3072
#define VV 32000
#define BB 8
#define NN 512
#define TT (BB*NN)

typedef __attribute__((ext_vector_type(8))) short bf16x8;
typedef __attribute__((ext_vector_type(4))) float f32x4;

// ---------- bf16 split helpers (RTNE) ----------
__device__ __forceinline__ unsigned short f2bf(float x) {
  unsigned u = __float_as_uint(x);
  unsigned r = u + 0x7FFFu + ((u >> 16) & 1u);
  return (unsigned short)(r >> 16);
}
__device__ __forceinline__ float bf2f(unsigned short h) {
  return __uint_as_float(((unsigned)h) << 16);
}

// ---------- async global->LDS 16B ----------
__device__ __forceinline__ void gl16(const void* g, void* l) {
  __builtin_amdgcn_global_load_lds(
      (const __attribute__((address_space(1))) unsigned*)g,
      (__attribute__((address_space(3))) unsigned*)l, 16, 0, 0);
}

// ---------- block-wide sum reduction of two values (256 threads = 4 waves) ----------
__device__ __forceinline__ void blockReduce2(float& a, float& b, float* sh) {
#pragma unroll
  for (int off = 32; off > 0; off >>= 1) {
    a += __shfl_down(a, off, 64);
    b += __shfl_down(b, off, 64);
  }
  int lane = threadIdx.x & 63;
  int w = threadIdx.x >> 6;
  if (lane == 0) { sh[2*w] = a; sh[2*w+1] = b; }
  __syncthreads();
  a = sh[0] + sh[2] + sh[4] + sh[6];
  b = sh[1] + sh[3] + sh[5] + sh[7];
}

// ---------- embedding gather + sinusoid PE + LayerNorm (+ optional bf16 split out) ----------
__global__ __launch_bounds__(256) void k_embed_ln(const float* __restrict__ emb,
    const float* __restrict__ g, const float* __restrict__ bb,
    const int* __restrict__ x, float* __restrict__ out,
    unsigned short* __restrict__ ohi, unsigned short* __restrict__ olo) {
  __shared__ float sh[8];
  int tok = blockIdx.x;
  int n = tok & (NN - 1);
  int t = x[tok];
  const float* row = emb + (size_t)t * DD;
  float v[3]; float s = 0.f, ss = 0.f;
#pragma unroll
  for (int i = 0; i < 3; ++i) {
    int d = threadIdx.x + 256 * i;
    int pair = d >> 1;
    float div = expf((float)(2 * pair) * (-9.210340371976184f / (float)DD));
    float ang = (float)n * div;
    float pe = (d & 1) ? cosf(ang) : sinf(ang);
    float val = row[d] + pe;
    v[i] = val; s += val; ss += val * val;
  }
  blockReduce2(s, ss, sh);
  float mu = s * (1.f / DD);
  float var = ss * (1.f / DD) - mu * mu;
  float rs = rsqrtf(var + 1e-5f);
#pragma unroll
  for (int i = 0; i < 3; ++i) {
    int d = threadIdx.x + 256 * i;
    float val = (v[i] - mu) * rs * g[d] + bb[d];
    size_t idx = (size_t)tok * DD + d;
    out[idx] = val;
    if (ohi) { unsigned short h = f2bf(val); ohi[idx] = h; olo[idx] = f2bf(val - bf2f(h)); }
  }
}

// ---------- LayerNorm of (in0 [+ in1]) with optional fp32 / split outputs ----------
__global__ __launch_bounds__(256) void k_ln(const float* __restrict__ in0,
    const float* __restrict__ in1, const float* __restrict__ g,
    const float* __restrict__ bb, float* __restrict__ outf,
    unsigned short* __restrict__ ohi, unsigned short* __restrict__ olo) {
  __shared__ float sh[8];
  int tok = blockIdx.x;
  float v[3]; float s = 0.f, ss = 0.f;
#pragma unroll
  for (int i = 0; i < 3; ++i) {
    int d = threadIdx.x + 256 * i;
    float val = in0[(size_t)tok * DD + d];
    if (in1) val += in1[(size_t)tok * DD + d];
    v[i] = val; s += val; ss += val * val;
  }
  blockReduce2(s, ss, sh);
  float mu = s * (1.f / DD);
  float var = ss * (1.f / DD) - mu * mu;
  float rs = rsqrtf(var + 1e-5f);
#pragma unroll
  for (int i = 0; i < 3; ++i) {
    int d = threadIdx.x + 256 * i;
    float val = (v[i] - mu) * rs * g[d] + bb[d];
    size_t idx = (size_t)tok * DD + d;
    if (outf) outf[idx] = val;
    if (ohi) { unsigned short h = f2bf(val); ohi[idx] = h; olo[idx] = f2bf(val - bf2f(h)); }
  }
}

// ---------- RoPE in-place on q,k of qkv (first 32 dims/head) ----------
__global__ __launch_bounds__(384) void k_rope(float* __restrict__ qkv) {
  int tok = blockIdx.x;
  int n = tok & (NN - 1);
  int tid = threadIdx.x;
  int qk = tid / 192;
  int rem = tid - qk * 192;
  int head = rem >> 4;
  int i = rem & 15;
  size_t base = (size_t)tok * (3 * DD) + (size_t)qk * DD + head * DHH + 2 * i;
  float inv = expf(-0.57564627324851148f * (float)i);
  float ang = (float)n * inv;
  float c = cosf(ang), sn = sinf(ang);
  float x0 = qkv[base], x1 = qkv[base + 1];
  qkv[base]     = x0 * c - x1 * sn;
  qkv[base + 1] = x1 * c + x0 * sn;
}

// ---------- flash attention: one block = 32 query rows of one (b,h) ----------
__global__ __launch_bounds__(256) void k_attn(const float* __restrict__ qkv,
    const int* __restrict__ x, float* __restrict__ outf,
    unsigned short* __restrict__ ohi, unsigned short* __restrict__ olo) {
  __shared__ float qs[32][68];
  __shared__ float Ks[64][68];
  __shared__ float Vs[64][68];
  __shared__ float ps[32][65];
  __shared__ float maskv[64];
  int blk = blockIdx.x;
  int rb = blk & 15;
  int hh = (blk >> 4) % HH;
  int b = blk / (16 * HH);
  int i0 = rb * 32;
  int tid = threadIdx.x;
  int r = tid >> 3;
  int l8 = tid & 7;
  {
    int c8 = l8 * 8;
    const float* qp = qkv + (size_t)(b * NN + i0 + r) * (3 * DD) + hh * DHH + c8;
    *(float4*)&qs[r][c8] = *(const float4*)qp;
    *(float4*)&qs[r][c8 + 4] = *(const float4*)(qp + 4);
  }
  float m_run = -INFINITY, l_run = 0.f;
  float o[8] = {0.f,0.f,0.f,0.f,0.f,0.f,0.f,0.f};
  int kr = tid >> 2;
  int kc = (tid & 3) * 16;
  for (int kt = 0; kt < NN; kt += 64) {
    __syncthreads();
    {
      const float* kp = qkv + (size_t)(b * NN + kt + kr) * (3 * DD) + DD + hh * DHH + kc;
      const float* vp = kp + DD;
#pragma unroll
      for (int q4 = 0; q4 < 4; ++q4) {
        *(float4*)&Ks[kr][kc + 4 * q4] = *(const float4*)(kp + 4 * q4);
        *(float4*)&Vs[kr][kc + 4 * q4] = *(const float4*)(vp + 4 * q4);
      }
    }
    if (tid < 64) maskv[tid] = (x[b * NN + kt + tid] == 0) ? 1.f : 0.f;
    __syncthreads();
    float sv[8];
#pragma unroll
    for (int jj = 0; jj < 8; ++jj) {
      int j = jj * 8 + l8;
      float4 acc = make_float4(0.f, 0.f, 0.f, 0.f);
#pragma unroll
      for (int dq = 0; dq < 16; ++dq) {
        float4 kq = *(const float4*)&Ks[j][4 * dq];
        float4 qq = *(const float4*)&qs[r][4 * dq];
        acc.x = fmaf(kq.x, qq.x, acc.x);
        acc.y = fmaf(kq.y, qq.y, acc.y);
        acc.z = fmaf(kq.z, qq.z, acc.z);
        acc.w = fmaf(kq.w, qq.w, acc.w);
      }
      float sd = ((acc.x + acc.y) + (acc.z + acc.w)) * 0.125f;
      if (maskv[j] != 0.f) sd = 1e-9f;
      sv[jj] = sd;
    }
    float tm = sv[0];
#pragma unroll
    for (int jj = 1; jj < 8; ++jj) tm = fmaxf(tm, sv[jj]);
    tm = fmaxf(tm, __shfl_xor(tm, 1, 64));
    tm = fmaxf(tm, __shfl_xor(tm, 2, 64));
    tm = fmaxf(tm, __shfl_xor(tm, 4, 64));
    float m_new = fmaxf(m_run, tm);
    float fs = expf(m_run - m_new);
    float tsum = 0.f;
#pragma unroll
    for (int jj = 0; jj < 8; ++jj) {
      float p = expf(sv[jj] - m_new);
      ps[r][jj * 8 + l8] = p;
      tsum += p;
    }
    tsum += __shfl_xor(tsum, 1, 64);
    tsum += __shfl_xor(tsum, 2, 64);
    tsum += __shfl_xor(tsum, 4, 64);
    l_run = l_run * fs + tsum;
    m_run = m_new;
#pragma unroll
    for (int dd = 0; dd < 8; ++dd) o[dd] *= fs;
    __syncthreads();
#pragma unroll 8
    for (int j = 0; j < 64; ++j) {
      float p = ps[r][j];
      float4 v0 = *(const float4*)&Vs[j][l8 * 8];
      float4 v1 = *(const float4*)&Vs[j][l8 * 8 + 4];
      o[0] = fmaf(p, v0.x, o[0]);
      o[1] = fmaf(p, v0.y, o[1]);
      o[2] = fmaf(p, v0.z, o[2]);
      o[3] = fmaf(p, v0.w, o[3]);
      o[4] = fmaf(p, v1.x, o[4]);
      o[5] = fmaf(p, v1.y, o[5]);
      o[6] = fmaf(p, v1.z, o[6]);
      o[7] = fmaf(p, v1.w, o[7]);
    }
  }
  float invl = 1.f / l_run;
  size_t base = (size_t)(b * NN + i0 + r) * DD + hh * DHH + l8 * 8;
  if (ohi) {
    bf16x8 hv, lv;
#pragma unroll
    for (int dd = 0; dd < 8; ++dd) {
      float v = o[dd] * invl;
      unsigned short h = f2bf(v);
      hv[dd] = (short)h; lv[dd] = (short)f2bf(v - bf2f(h));
    }
    *(bf16x8*)&ohi[base] = hv;
    *(bf16x8*)&olo[base] = lv;
  } else {
    float* op = outf + base;
    *(float4*)op = make_float4(o[0]*invl, o[1]*invl, o[2]*invl, o[3]*invl);
    *(float4*)(op + 4) = make_float4(o[4]*invl, o[5]*invl, o[6]*invl, o[7]*invl);
  }
}

// ---------- weight transpose + bf16 hi/lo split: W[K][N] -> Wt{hi,lo}[N][K] ----------
__global__ __launch_bounds__(256) void k_wsplit(const float* __restrict__ W,
    unsigned short* __restrict__ Whi, unsigned short* __restrict__ Wlo, int K, int N) {
  __shared__ float tile[64][65];
  int k0 = blockIdx.y * 64, n0 = blockIdx.x * 64;
  int tid = threadIdx.x;
#pragma unroll
  for (int it = 0; it < 4; ++it) {
    int r = (tid >> 4) + it * 16;
    int c = (tid & 15) * 4;
    float4 v = *(const float4*)&W[(size_t)(k0 + r) * N + n0 + c];
    tile[r][c] = v.x; tile[r][c+1] = v.y; tile[r][c+2] = v.z; tile[r][c+3] = v.w;
  }
  __syncthreads();
  int n = tid >> 2;
  int kb = (tid & 3) * 16;
  bf16x8 h0, h1, l0, l1;
#pragma unroll
  for (int i = 0; i < 8; ++i) {
    float xv = tile[kb + i][n];
    unsigned short h = f2bf(xv);
    h0[i] = (short)h; l0[i] = (short)f2bf(xv - bf2f(h));
  }
#pragma unroll
  for (int i = 0; i < 8; ++i) {
    float xv = tile[kb + 8 + i][n];
    unsigned short h = f2bf(xv);
    h1[i] = (short)h; l1[i] = (short)f2bf(xv - bf2f(h));
  }
  size_t ob = (size_t)(n0 + n) * K + k0 + kb;
  *(bf16x8*)&Whi[ob] = h0; *(bf16x8*)&Whi[ob + 8] = h1;
  *(bf16x8*)&Wlo[ob] = l0; *(bf16x8*)&Wlo[ob + 8] = l1;
}

// ---------- split-bf16 MFMA GEMM: C[T x Nc] = A @ W  (A[t][k] hi/lo, W[n][k] hi/lo) ----------
// 128x128 tile, BK=32, 4 waves (2x2), 4x4 16x16 frags per wave, 3 MFMAs per frag (hi*hi+hi*lo+lo*hi)
template<int ACT, int SPLIT>
__global__ __launch_bounds__(256) void k_mgemm(
    const unsigned short* __restrict__ Ahi, const unsigned short* __restrict__ Alo,
    const unsigned short* __restrict__ Whi, const unsigned short* __restrict__ Wlo,
    const float* __restrict__ bias, float* __restrict__ C,
    unsigned short* __restrict__ Chi, unsigned short* __restrict__ Clo,
    int K, int Nc) {
  __shared__ unsigned short AsH[128*32], AsL[128*32], BsH[128*32], BsL[128*32];
  int tid = threadIdx.x;
  int w = tid >> 6, l = tid & 63;
  int wr = w >> 1, wc = w & 1;
  int brow = blockIdx.y * 128, bcol = blockIdx.x * 128;
  int lr = l & 15;      // frag row/col within 16
  int lk = l >> 4;      // k-group (8 bf16 each)
  int srow = w * 16 + (l >> 2);
  int skc = (l & 3) * 8;
  const unsigned short* pAh = Ahi + (size_t)(brow + srow) * K + skc;
  const unsigned short* pAl = Alo + (size_t)(brow + srow) * K + skc;
  const unsigned short* pBh = Whi + (size_t)(bcol + srow) * K + skc;
  const unsigned short* pBl = Wlo + (size_t)(bcol + srow) * K + skc;
  size_t half = (size_t)64 * K;
  f32x4 acc[4][4];
#pragma unroll
  for (int i = 0; i < 4; ++i)
#pragma unroll
    for (int j = 0; j < 4; ++j) acc[i][j] = (f32x4){0.f, 0.f, 0.f, 0.f};
  int sAo = srow * 32 + skc;
  for (int k0 = 0; k0 < K; k0 += 32) {
    __syncthreads();
    gl16(pAh, &AsH[sAo]); gl16(pAh + half, &AsH[sAo + 64*32]);
    gl16(pAl, &AsL[sAo]); gl16(pAl + half, &AsL[sAo + 64*32]);
    gl16(pBh, &BsH[sAo]); gl16(pBh + half, &BsH[sAo + 64*32]);
    gl16(pBl, &BsL[sAo]); gl16(pBl + half, &BsL[sAo + 64*32]);
    pAh += 32; pAl += 32; pBh += 32; pBl += 32;
    __syncthreads();
    bf16x8 ah[4], al[4], bh[4], bl[4];
#pragma unroll
    for (int i = 0; i < 4; ++i) {
      int ar = (wr*64 + i*16 + lr) * 32 + lk*8;
      int br = (wc*64 + i*16 + lr) * 32 + lk*8;
      ah[i] = *(const bf16x8*)&AsH[ar];
      al[i] = *(const bf16x8*)&AsL[ar];
      bh[i] = *(const bf16x8*)&BsH[br];
      bl[i] = *(const bf16x8*)&BsL[br];
    }
#pragma unroll
    for (int mi = 0; mi < 4; ++mi)
#pragma unroll
      for (int ni = 0; ni < 4; ++ni) {
        acc[mi][ni] = __builtin_amdgcn_mfma_f32_16x16x32_bf16(ah[mi], bh[ni], acc[mi][ni], 0, 0, 0);
        acc[mi][ni] = __builtin_amdgcn_mfma_f32_16x16x32_bf16(ah[mi], bl[ni], acc[mi][ni], 0, 0, 0);
        acc[mi][ni] = __builtin_amdgcn_mfma_f32_16x16x32_bf16(al[mi], bh[ni], acc[mi][ni], 0, 0, 0);
      }
  }
#pragma unroll
  for (int mi = 0; mi < 4; ++mi) {
    int row0 = brow + wr*64 + mi*16 + lk*4;
#pragma unroll
    for (int ni = 0; ni < 4; ++ni) {
      int col = bcol + wc*64 + ni*16 + lr;
      float bv = bias ? bias[col] : 0.f;
#pragma unroll
      for (int r = 0; r < 4; ++r) {
        float v = acc[mi][ni][r] + bv;
        if (ACT == 1) v = 0.5f * v * (1.f + erff(v * 0.70710678118654752f));
        size_t idx = (size_t)(row0 + r) * Nc + col;
        if (SPLIT == 1) {
          unsigned short h = f2bf(v);
          Chi[idx] = h; Clo[idx] = f2bf(v - bf2f(h));
        } else {
          C[idx] = v;
        }
      }
    }
  }
}

// ---------- fp32 SGEMM (fallback path) ----------
template<int ACT>
__global__ __launch_bounds__(256) void k_gemm(const float* __restrict__ A,
    const float* __restrict__ W, const float* __restrict__ bias,
    float* __restrict__ C, int K, int Nc) {
  __shared__ float As[16][128];
  __shared__ float Bs[16][64];
  int tid = threadIdx.x;
  int bm = blockIdx.y * 128;
  int bn = blockIdx.x * 64;
  int tmi = tid & 31;
  int tni = tid >> 5;
  int arow = tid >> 2;
  int akq = (tid & 3) * 4;
  int bn4 = (tid & 15) * 4;
  int bkb = tid >> 4;
  const float* pA0 = A + (size_t)(bm + arow) * K + akq;
  const float* pA1 = A + (size_t)(bm + arow + 64) * K + akq;
  const float* pB  = W + (size_t)bkb * Nc + bn + bn4;
  float acc[4][8];
#pragma unroll
  for (int i = 0; i < 4; ++i)
#pragma unroll
    for (int j = 0; j < 8; ++j) acc[i][j] = 0.f;
  for (int k0 = 0; k0 < K; k0 += 16) {
    float4 a0 = *(const float4*)pA0;
    float4 a1 = *(const float4*)pA1;
    float4 b0 = *(const float4*)pB;
    __syncthreads();
    As[akq + 0][arow] = a0.x; As[akq + 1][arow] = a0.y;
    As[akq + 2][arow] = a0.z; As[akq + 3][arow] = a0.w;
    As[akq + 0][arow + 64] = a1.x; As[akq + 1][arow + 64] = a1.y;
    As[akq + 2][arow + 64] = a1.z; As[akq + 3][arow + 64] = a1.w;
    *(float4*)&Bs[bkb][bn4] = b0;
    __syncthreads();
#pragma unroll
    for (int kk = 0; kk < 16; ++kk) {
      float4 av  = *(const float4*)&As[kk][tmi * 4];
      float4 bv0 = *(const float4*)&Bs[kk][tni * 8];
      float4 bv1 = *(const float4*)&Bs[kk][tni * 8 + 4];
      float am[4] = {av.x, av.y, av.z, av.w};
      float bw[8] = {bv0.x, bv0.y, bv0.z, bv0.w, bv1.x, bv1.y, bv1.z, bv1.w};
#pragma unroll
      for (int mi = 0; mi < 4; ++mi)
#pragma unroll
        for (int nj = 0; nj < 8; ++nj)
          acc[mi][nj] = fmaf(am[mi], bw[nj], acc[mi][nj]);
    }
    pA0 += 16; pA1 += 16; pB += (size_t)16 * Nc;
  }
#pragma unroll
  for (int mi = 0; mi < 4; ++mi) {
    int rowv = bm + tmi * 4 + mi;
    float* cp = C + (size_t)rowv * Nc + bn + tni * 8;
    float vals[8];
#pragma unroll
    for (int nj = 0; nj < 8; ++nj) {
      float vv = acc[mi][nj];
      if (bias) vv += bias[bn + tni * 8 + nj];
      if (ACT == 1) vv = 0.5f * vv * (1.f + erff(vv * 0.70710678118654752f));
      vals[nj] = vv;
    }
    *(float4*)cp = make_float4(vals[0], vals[1], vals[2], vals[3]);
    *(float4*)(cp + 4) = make_float4(vals[4], vals[5], vals[6], vals[7]);
  }
}

// ---------- copy h[:,0,:] to second output ----------
__global__ void k_copyh0(const float* __restrict__ h, float* __restrict__ o2) {
  int i = blockIdx.x * 256 + threadIdx.x;
  if (i < BB * DD) {
    int b = i / DD, d = i - b * DD;
    o2[i] = h[(size_t)(b * NN) * DD + d];
  }
}

extern "C" void kernel_launch(void* const* d_in, const int* in_sizes, int n_in,
                              void* d_out, int out_size, void* d_ws, size_t ws_size,
                              hipStream_t stream) {
  const float* tok_emb = (const float*)d_in[0];
  const float* emb_g  = (const float*)d_in[1];
  const float* emb_b  = (const float*)d_in[2];
  const float* n1_g   = (const float*)d_in[3];
  const float* n1_b   = (const float*)d_in[4];
  const float* n2_g   = (const float*)d_in[5];
  const float* n2_b   = (const float*)d_in[6];
  const float* qkv_w  = (const float*)d_in[7];
  const float* out_w  = (const float*)d_in[8];
  const float* ff_g   = (const float*)d_in[9];
  const float* ff_b   = (const float*)d_in[10];
  const float* ff_w1  = (const float*)d_in[11];
  const float* ff_b1  = (const float*)d_in[12];
  const float* ff_w2  = (const float*)d_in[13];
  const float* ff_b2  = (const float*)d_in[14];
  const float* h_w1   = (const float*)d_in[15];
  const float* h_b1   = (const float*)d_in[16];
  const float* h_g    = (const float*)d_in[17];
  const float* h_b    = (const float*)d_in[18];
  const float* h_w2   = (const float*)d_in[19];
  const float* h_b2   = (const float*)d_in[20];
  const int*   xi     = (const int*)d_in[21];
  float* outp = (float*)d_out;

  size_t szH  = (size_t)TT * DD;          // floats
  size_t szT1 = (size_t)TT * 3 * DD;      // floats
  size_t szAM = (size_t)TT * MFF;         // ushorts per split buffer
  size_t szW  = (size_t)DD * VV;          // ushorts per split buffer
  size_t need = (szH + szT1 + szH) * 4 + szAM * 2 * 4 + szW * 2 * 2;

  if (ws_size >= need) {
    // -------- fast MFMA split-bf16 path --------
    char* p = (char*)d_ws;
    float* h  = (float*)p;            p += szH * 4;
    float* t1 = (float*)p;            p += szT1 * 4;
    float* t3 = (float*)p;            p += szH * 4;
    unsigned short* ahi = (unsigned short*)p; p += szAM * 2;
    unsigned short* alo = (unsigned short*)p; p += szAM * 2;
    unsigned short* bhi = (unsigned short*)p; p += szAM * 2;
    unsigned short* blo = (unsigned short*)p; p += szAM * 2;
    unsigned short* whi = (unsigned short*)p; p += szW * 2;
    unsigned short* wlo = (unsigned short*)p;

    k_embed_ln<<<TT, 256, 0, stream>>>(tok_emb, emb_g, emb_b, xi, h, ahi, alo);
    for (int l = 0; l < NLAYER; ++l) {
      k_wsplit<<<dim3(3*DD/64, DD/64), 256, 0, stream>>>(
          qkv_w + (size_t)l * DD * 3 * DD, whi, wlo, DD, 3*DD);
      k_mgemm<0,0><<<dim3(3*DD/128, TT/128), 256, 0, stream>>>(
          ahi, alo, whi, wlo, nullptr, t1, nullptr, nullptr, DD, 3*DD);
      k_rope<<<TT, 384, 0, stream>>>(t1);
      k_attn<<<BB * HH * (NN / 32), 256, 0, stream>>>(t1, xi, nullptr, ahi, alo);
      k_wsplit<<<dim3(DD/64, DD/64), 256, 0, stream>>>(
          out_w + (size_t)l * DD * DD, whi, wlo, DD, DD);
      k_mgemm<0,0><<<dim3(DD/128, TT/128), 256, 0, stream>>>(
          ahi, alo, whi, wlo, nullptr, t3, nullptr, nullptr, DD, DD);
      k_ln<<<TT, 256, 0, stream>>>(t3, h, n1_g, n1_b, h, nullptr, nullptr);
      k_ln<<<TT, 256, 0, stream>>>(h, nullptr, ff_g + (size_t)l*DD, ff_b + (size_t)l*DD,
                                   nullptr, ahi, alo);
      k_wsplit<<<dim3(MFF/64, DD/64), 256, 0, stream>>>(
          ff_w1 + (size_t)l * DD * MFF, whi, wlo, DD, MFF);
      k_mgemm<1,1><<<dim3(MFF/128, TT/128), 256, 0, stream>>>(
          ahi, alo, whi, wlo, ff_b1 + (size_t)l*MFF, nullptr, bhi, blo, DD, MFF);
      k_wsplit<<<dim3(DD/64, MFF/64), 256, 0, stream>>>(
          ff_w2 + (size_t)l * MFF * DD, whi, wlo, MFF, DD);
      k_mgemm<0,0><<<dim3(DD/128, TT/128), 256, 0, stream>>>(
          bhi, blo, whi, wlo, ff_b2 + (size_t)l*DD, t1, nullptr, nullptr, MFF, DD);
      k_ln<<<TT, 256, 0, stream>>>(t1, h, n2_g, n2_b, h, ahi, alo);
    }
    k_wsplit<<<dim3(DD/64, DD/64), 256, 0, stream>>>(h_w1, whi, wlo, DD, DD);
    k_mgemm<1,0><<<dim3(DD/128, TT/128), 256, 0, stream>>>(
        ahi, alo, whi, wlo, h_b1, t1, nullptr, nullptr, DD, DD);
    k_ln<<<TT, 256, 0, stream>>>(t1, nullptr, h_g, h_b, nullptr, ahi, alo);
    k_wsplit<<<dim3(VV/64, DD/64), 256, 0, stream>>>(h_w2, whi, wlo, DD, VV);
    k_mgemm<0,0><<<dim3(VV/128, TT/128), 256, 0, stream>>>(
        ahi, alo, whi, wlo, h_b2, outp, nullptr, nullptr, DD, VV);
    k_copyh0<<<(BB * DD + 255) / 256, 256, 0, stream>>>(h, outp + (size_t)TT * VV);
  } else {
    // -------- fallback fp32 path --------
    float* h  = (float*)d_ws;
    float* t1 = h  + szH;
    float* t2 = t1 + szT1;
    float* t3 = t2 + (size_t)TT * MFF;
    k_embed_ln<<<TT, 256, 0, stream>>>(tok_emb, emb_g, emb_b, xi, h, nullptr, nullptr);
    for (int l = 0; l < NLAYER; ++l) {
      k_gemm<0><<<dim3(3 * DD / 64, TT / 128), 256, 0, stream>>>(
          h, qkv_w + (size_t)l * DD * 3 * DD, nullptr, t1, DD, 3 * DD);
      k_rope<<<TT, 384, 0, stream>>>(t1);
      k_attn<<<BB * HH * (NN / 32), 256, 0, stream>>>(t1, xi, t2, nullptr, nullptr);
      k_gemm<0><<<dim3(DD / 64, TT / 128), 256, 0, stream>>>(
          t2, out_w + (size_t)l * DD * DD, nullptr, t3, DD, DD);
      k_ln<<<TT, 256, 0, stream>>>(t3, h, n1_g, n1_b, h, nullptr, nullptr);
      k_ln<<<TT, 256, 0, stream>>>(h, nullptr, ff_g + (size_t)l * DD, ff_b + (size_t)l * DD, t3, nullptr, nullptr);
      k_gemm<1><<<dim3(MFF / 64, TT / 128), 256, 0, stream>>>(
          t3, ff_w1 + (size_t)l * DD * MFF, ff_b1 + (size_t)l * MFF, t2, DD, MFF);
      k_gemm<0><<<dim3(DD / 64, TT / 128), 256, 0, stream>>>(
          t2, ff_w2 + (size_t)l * MFF * DD, ff_b2 + (size_t)l * DD, t1, MFF, DD);
      k_ln<<<TT, 256, 0, stream>>>(t1, h, n2_g, n2_b, h, nullptr, nullptr);
    }
    k_gemm<1><<<dim3(DD / 64, TT / 128), 256, 0, stream>>>(h, h_w1, h_b1, t1, DD, DD);
    k_ln<<<TT, 256, 0, stream>>>(t1, nullptr, h_g, h_b, t3, nullptr, nullptr);
    k_gemm<0><<<dim3(VV / 64, TT / 128), 256, 0, stream>>>(t3, h_w2, h_b2, outp, DD, VV);
    k_copyh0<<<(BB * DD + 255) / 256, 256, 0, stream>>>(h, outp + (size_t)TT * VV);
  }
}

// Round 3
// 5809.133 us; speedup vs baseline: 2.6283x; 1.3065x over previous
//
#include <hip/hip_runtime.h>
#include <math.h>

#define DD 768
#define HH 12
#define DHH 64
#define NLAYER 12
#define MFF 3072
#define VV 32000
#define BB 8
#define NN 512
#define TT (BB*NN)

typedef __attribute__((ext_vector_type(8))) short bf16x8;
typedef __attribute__((ext_vector_type(4))) float f32x4;

// ---------- bf16 split helpers (RTNE) ----------
__device__ __forceinline__ unsigned short f2bf(float x) {
  unsigned u = __float_as_uint(x);
  unsigned r = u + 0x7FFFu + ((u >> 16) & 1u);
  return (unsigned short)(r >> 16);
}
__device__ __forceinline__ float bf2f(unsigned short h) {
  return __uint_as_float(((unsigned)h) << 16);
}

// ---------- async global->LDS 16B ----------
__device__ __forceinline__ void gl16(const void* g, void* l) {
  __builtin_amdgcn_global_load_lds(
      (const __attribute__((address_space(1))) unsigned*)g,
      (__attribute__((address_space(3))) unsigned*)l, 16, 0, 0);
}

// ---------- block-wide sum reduction of two values (256 threads = 4 waves) ----------
__device__ __forceinline__ void blockReduce2(float& a, float& b, float* sh) {
#pragma unroll
  for (int off = 32; off > 0; off >>= 1) {
    a += __shfl_down(a, off, 64);
    b += __shfl_down(b, off, 64);
  }
  int lane = threadIdx.x & 63;
  int w = threadIdx.x >> 6;
  if (lane == 0) { sh[2*w] = a; sh[2*w+1] = b; }
  __syncthreads();
  a = sh[0] + sh[2] + sh[4] + sh[6];
  b = sh[1] + sh[3] + sh[5] + sh[7];
}

// ---------- embedding gather + sinusoid PE + LayerNorm (+ bf16 split out) ----------
__global__ __launch_bounds__(256) void k_embed_ln(const float* __restrict__ emb,
    const float* __restrict__ g, const float* __restrict__ bb,
    const int* __restrict__ x, float* __restrict__ out,
    unsigned short* __restrict__ ohi, unsigned short* __restrict__ olo) {
  __shared__ float sh[8];
  int tok = blockIdx.x;
  int n = tok & (NN - 1);
  int t = x[tok];
  const float* row = emb + (size_t)t * DD;
  float v[3]; float s = 0.f, ss = 0.f;
#pragma unroll
  for (int i = 0; i < 3; ++i) {
    int d = threadIdx.x + 256 * i;
    int pair = d >> 1;
    float div = expf((float)(2 * pair) * (-9.210340371976184f / (float)DD));
    float ang = (float)n * div;
    float pe = (d & 1) ? cosf(ang) : sinf(ang);
    float val = row[d] + pe;
    v[i] = val; s += val; ss += val * val;
  }
  blockReduce2(s, ss, sh);
  float mu = s * (1.f / DD);
  float var = ss * (1.f / DD) - mu * mu;
  float rs = rsqrtf(var + 1e-5f);
#pragma unroll
  for (int i = 0; i < 3; ++i) {
    int d = threadIdx.x + 256 * i;
    float val = (v[i] - mu) * rs * g[d] + bb[d];
    size_t idx = (size_t)tok * DD + d;
    out[idx] = val;
    unsigned short h = f2bf(val); ohi[idx] = h; olo[idx] = f2bf(val - bf2f(h));
  }
}

// ---------- LayerNorm of (in0 [+ in1]) with optional fp32 / split outputs ----------
__global__ __launch_bounds__(256) void k_ln(const float* __restrict__ in0,
    const float* __restrict__ in1, const float* __restrict__ g,
    const float* __restrict__ bb, float* __restrict__ outf,
    unsigned short* __restrict__ ohi, unsigned short* __restrict__ olo) {
  __shared__ float sh[8];
  int tok = blockIdx.x;
  float v[3]; float s = 0.f, ss = 0.f;
#pragma unroll
  for (int i = 0; i < 3; ++i) {
    int d = threadIdx.x + 256 * i;
    float val = in0[(size_t)tok * DD + d];
    if (in1) val += in1[(size_t)tok * DD + d];
    v[i] = val; s += val; ss += val * val;
  }
  blockReduce2(s, ss, sh);
  float mu = s * (1.f / DD);
  float var = ss * (1.f / DD) - mu * mu;
  float rs = rsqrtf(var + 1e-5f);
#pragma unroll
  for (int i = 0; i < 3; ++i) {
    int d = threadIdx.x + 256 * i;
    float val = (v[i] - mu) * rs * g[d] + bb[d];
    size_t idx = (size_t)tok * DD + d;
    if (outf) outf[idx] = val;
    if (ohi) { unsigned short h = f2bf(val); ohi[idx] = h; olo[idx] = f2bf(val - bf2f(h)); }
  }
}

// ---------- fused: y1 = LN(in0+res)*g1+b1 -> outf;  y2 = LN(y1)*g2+b2 -> split ----------
__global__ __launch_bounds__(256) void k_ln2(const float* __restrict__ in0,
    const float* __restrict__ res, const float* __restrict__ g1,
    const float* __restrict__ b1v, const float* __restrict__ g2,
    const float* __restrict__ b2v, float* __restrict__ outf,
    unsigned short* __restrict__ ohi, unsigned short* __restrict__ olo) {
  __shared__ float sh[8];
  int tok = blockIdx.x;
  float v[3]; float s = 0.f, ss = 0.f;
#pragma unroll
  for (int i = 0; i < 3; ++i) {
    int d = threadIdx.x + 256 * i;
    float val = in0[(size_t)tok * DD + d] + res[(size_t)tok * DD + d];
    v[i] = val; s += val; ss += val * val;
  }
  blockReduce2(s, ss, sh);
  float mu = s * (1.f / DD);
  float var = ss * (1.f / DD) - mu * mu;
  float rs = rsqrtf(var + 1e-5f);
  float y[3]; float s2 = 0.f, ss2 = 0.f;
#pragma unroll
  for (int i = 0; i < 3; ++i) {
    int d = threadIdx.x + 256 * i;
    float yy = (v[i] - mu) * rs * g1[d] + b1v[d];
    y[i] = yy; s2 += yy; ss2 += yy * yy;
    outf[(size_t)tok * DD + d] = yy;
  }
  __syncthreads();   // sh reuse
  blockReduce2(s2, ss2, sh);
  float mu2 = s2 * (1.f / DD);
  float var2 = ss2 * (1.f / DD) - mu2 * mu2;
  float rs2 = rsqrtf(var2 + 1e-5f);
#pragma unroll
  for (int i = 0; i < 3; ++i) {
    int d = threadIdx.x + 256 * i;
    float val = (y[i] - mu2) * rs2 * g2[d] + b2v[d];
    size_t idx = (size_t)tok * DD + d;
    unsigned short h = f2bf(val); ohi[idx] = h; olo[idx] = f2bf(val - bf2f(h));
  }
}

// ---------- RoPE on 8 packed bf16 (4 pairs), pair base pbase ----------
__device__ __forceinline__ void rope8(bf16x8& v, int pbase, float npos) {
#pragma unroll
  for (int i = 0; i < 4; ++i) {
    float inv = expf(-0.57564627324851148f * (float)(pbase + i)); // 10000^(-p/16)
    float ang = npos * inv;
    float sn, cs;
    __sincosf(ang, &sn, &cs);
    float x0 = bf2f((unsigned short)v[2*i]);
    float x1 = bf2f((unsigned short)v[2*i+1]);
    v[2*i]   = (short)f2bf(x0 * cs - x1 * sn);
    v[2*i+1] = (short)f2bf(x1 * cs + x0 * sn);
  }
}

// ---------- MFMA flash attention: block = 64 q rows of one (b,h), 4 waves x 16 rows ----------
// qkvb: bf16 [TT][3*DD] (q|k|v). RoPE applied on the fly. Output: split bf16.
__global__ __launch_bounds__(256) void k_attn(const unsigned short* __restrict__ qkvb,
    const int* __restrict__ x,
    unsigned short* __restrict__ ohi, unsigned short* __restrict__ olo) {
  __shared__ unsigned short Ks[64][72];      // K[key][d]
  __shared__ unsigned short Vt[64][72];      // V^T[d][key]
  __shared__ unsigned short Ps[4][16][72];   // per-wave P[q][key]
  __shared__ float maskv[64];
  int blk = blockIdx.x;
  int qb = blk & 7;
  int hh = (blk >> 3) % HH;
  int b = blk / (8 * HH);
  int q0 = qb * 64;
  int tid = threadIdx.x;
  int w = tid >> 6, l = tid & 63;
  int g = l >> 4, c = l & 15;

  // Q fragments (A operand): row=c -> q = q0+16w+c ; k-dim = d = 8g+i (+32)
  bf16x8 qa0, qa1;
  {
    int q = q0 + 16 * w + c;
    const unsigned short* qp = qkvb + (size_t)(b * NN + q) * (3 * DD) + hh * DHH;
    qa0 = *(const bf16x8*)(qp + 8 * g);
    qa1 = *(const bf16x8*)(qp + 32 + 8 * g);
    rope8(qa0, 4 * g, (float)q);              // dims 8g..8g+7 (<32) rotated
  }
  f32x4 o[4];
#pragma unroll
  for (int f = 0; f < 4; ++f) o[f] = (f32x4){0.f,0.f,0.f,0.f};
  float m_run[4] = {-INFINITY,-INFINITY,-INFINITY,-INFINITY};
  float l_run[4] = {0.f,0.f,0.f,0.f};

  int kr = tid >> 2;              // staging: key row 0..63
  int kd = (tid & 3) * 16;        // d segment
  for (int kt = 0; kt < NN; kt += 64) {
    __syncthreads();   // all waves done with prev Ks/Vt
    {
      int tok = b * NN + kt + kr;
      const unsigned short* kp = qkvb + (size_t)tok * (3 * DD) + DD + hh * DHH + kd;
      const unsigned short* vp = kp + DD;
      bf16x8 k0 = *(const bf16x8*)kp;
      bf16x8 k1 = *(const bf16x8*)(kp + 8);
      if (kd < 32) {               // kd in {0,16}: dims kd..kd+15 all rotated
        float npos = (float)(kt + kr);
        rope8(k0, kd / 2, npos);
        rope8(k1, kd / 2 + 4, npos);
      }
      *(bf16x8*)&Ks[kr][kd] = k0;
      *(bf16x8*)&Ks[kr][kd + 8] = k1;
      bf16x8 v0 = *(const bf16x8*)vp;
      bf16x8 v1 = *(const bf16x8*)(vp + 8);
#pragma unroll
      for (int j = 0; j < 8; ++j) {
        Vt[kd + j][kr] = (unsigned short)v0[j];
        Vt[kd + 8 + j][kr] = (unsigned short)v1[j];
      }
    }
    if (tid < 64) maskv[tid] = (x[b * NN + kt + tid] == 0) ? 1.f : 0.f;
    __syncthreads();

    // ---- S = (Q K^T) * scale, masked ----
    f32x4 sc[4];
#pragma unroll
    for (int f = 0; f < 4; ++f) {
      bf16x8 kb0 = *(const bf16x8*)&Ks[16 * f + c][8 * g];
      bf16x8 kb1 = *(const bf16x8*)&Ks[16 * f + c][32 + 8 * g];
      f32x4 sacc = (f32x4){0.f,0.f,0.f,0.f};
      sacc = __builtin_amdgcn_mfma_f32_16x16x32_bf16(qa0, kb0, sacc, 0, 0, 0);
      sacc = __builtin_amdgcn_mfma_f32_16x16x32_bf16(qa1, kb1, sacc, 0, 0, 0);
      float mk = maskv[16 * f + c];
#pragma unroll
      for (int r = 0; r < 4; ++r) {
        float sv = sacc[r] * 0.125f;
        sacc[r] = (mk != 0.f) ? 1e-9f : sv;
      }
      sc[f] = sacc;
    }
    // ---- online softmax (rows 4g+r; reduce over 16 lanes c) ----
    float fs[4];
#pragma unroll
    for (int r = 0; r < 4; ++r) {
      float m = fmaxf(fmaxf(sc[0][r], sc[1][r]), fmaxf(sc[2][r], sc[3][r]));
      m = fmaxf(m, __shfl_xor(m, 1, 64));
      m = fmaxf(m, __shfl_xor(m, 2, 64));
      m = fmaxf(m, __shfl_xor(m, 4, 64));
      m = fmaxf(m, __shfl_xor(m, 8, 64));
      float mn = fmaxf(m_run[r], m);
      fs[r] = expf(m_run[r] - mn);
      m_run[r] = mn;
    }
    float tsum[4] = {0.f,0.f,0.f,0.f};
#pragma unroll
    for (int f = 0; f < 4; ++f)
#pragma unroll
      for (int r = 0; r < 4; ++r) {
        float p = expf(sc[f][r] - m_run[r]);
        Ps[w][4 * g + r][16 * f + c] = f2bf(p);
        tsum[r] += p;
      }
#pragma unroll
    for (int r = 0; r < 4; ++r) {
      float t = tsum[r];
      t += __shfl_xor(t, 1, 64);
      t += __shfl_xor(t, 2, 64);
      t += __shfl_xor(t, 4, 64);
      t += __shfl_xor(t, 8, 64);
      l_run[r] = l_run[r] * fs[r] + t;
#pragma unroll
      for (int f = 0; f < 4; ++f) o[f][r] *= fs[r];
    }
    // ensure this wave's Ps writes are visible to its own cross-lane reads
    asm volatile("s_waitcnt lgkmcnt(0)" ::: "memory");
    __builtin_amdgcn_sched_barrier(0);
    // ---- O += P V : A = P (row=c=q, k=key), B = Vt (col=d, k=key) ----
    bf16x8 pa0 = *(const bf16x8*)&Ps[w][c][8 * g];
    bf16x8 pa1 = *(const bf16x8*)&Ps[w][c][32 + 8 * g];
#pragma unroll
    for (int f = 0; f < 4; ++f) {
      bf16x8 vb0 = *(const bf16x8*)&Vt[16 * f + c][8 * g];
      bf16x8 vb1 = *(const bf16x8*)&Vt[16 * f + c][32 + 8 * g];
      o[f] = __builtin_amdgcn_mfma_f32_16x16x32_bf16(pa0, vb0, o[f], 0, 0, 0);
      o[f] = __builtin_amdgcn_mfma_f32_16x16x32_bf16(pa1, vb1, o[f], 0, 0, 0);
    }
  }
  // ---- epilogue: normalize, split-bf16 store ----
#pragma unroll
  for (int r = 0; r < 4; ++r) {
    int tok = b * NN + q0 + 16 * w + 4 * g + r;
    float invl = 1.f / l_run[r];
#pragma unroll
    for (int f = 0; f < 4; ++f) {
      float vv = o[f][r] * invl;
      size_t idx = (size_t)tok * DD + hh * DHH + 16 * f + c;
      unsigned short h = f2bf(vv);
      ohi[idx] = h; olo[idx] = f2bf(vv - bf2f(h));
    }
  }
}

// ---------- weight transpose + bf16 hi/lo split: W[K][N] -> Wt{hi,lo}[N][K] ----------
__global__ __launch_bounds__(256) void k_wsplit(const float* __restrict__ W,
    unsigned short* __restrict__ Whi, unsigned short* __restrict__ Wlo, int K, int N) {
  __shared__ float tile[64][65];
  int k0 = blockIdx.y * 64, n0 = blockIdx.x * 64;
  int tid = threadIdx.x;
#pragma unroll
  for (int it = 0; it < 4; ++it) {
    int r = (tid >> 4) + it * 16;
    int c = (tid & 15) * 4;
    float4 v = *(const float4*)&W[(size_t)(k0 + r) * N + n0 + c];
    tile[r][c] = v.x; tile[r][c+1] = v.y; tile[r][c+2] = v.z; tile[r][c+3] = v.w;
  }
  __syncthreads();
  int n = tid >> 2;
  int kb = (tid & 3) * 16;
  bf16x8 h0, h1, l0, l1;
#pragma unroll
  for (int i = 0; i < 8; ++i) {
    float xv = tile[kb + i][n];
    unsigned short h = f2bf(xv);
    h0[i] = (short)h; l0[i] = (short)f2bf(xv - bf2f(h));
  }
#pragma unroll
  for (int i = 0; i < 8; ++i) {
    float xv = tile[kb + 8 + i][n];
    unsigned short h = f2bf(xv);
    h1[i] = (short)h; l1[i] = (short)f2bf(xv - bf2f(h));
  }
  size_t ob = (size_t)(n0 + n) * K + k0 + kb;
  *(bf16x8*)&Whi[ob] = h0; *(bf16x8*)&Whi[ob + 8] = h1;
  *(bf16x8*)&Wlo[ob] = l0; *(bf16x8*)&Wlo[ob + 8] = l1;
}

// ---------- split-bf16 MFMA GEMM: C[T x Nc] = A @ W ----------
// SPLIT: 0 = fp32 out, 1 = split hi/lo out, 2 = plain bf16 out (Chi)
template<int ACT, int SPLIT>
__global__ __launch_bounds__(256) void k_mgemm(
    const unsigned short* __restrict__ Ahi, const unsigned short* __restrict__ Alo,
    const unsigned short* __restrict__ Whi, const unsigned short* __restrict__ Wlo,
    const float* __restrict__ bias, float* __restrict__ C,
    unsigned short* __restrict__ Chi, unsigned short* __restrict__ Clo,
    int K, int Nc) {
  __shared__ unsigned short AsH[128*32], AsL[128*32], BsH[128*32], BsL[128*32];
  int tid = threadIdx.x;
  int w = tid >> 6, l = tid & 63;
  int wr = w >> 1, wc = w & 1;
  int brow = blockIdx.y * 128, bcol = blockIdx.x * 128;
  int lr = l & 15;
  int lk = l >> 4;
  int srow = w * 16 + (l >> 2);
  int skc = (l & 3) * 8;
  const unsigned short* pAh = Ahi + (size_t)(brow + srow) * K + skc;
  const unsigned short* pAl = Alo + (size_t)(brow + srow) * K + skc;
  const unsigned short* pBh = Whi + (size_t)(bcol + srow) * K + skc;
  const unsigned short* pBl = Wlo + (size_t)(bcol + srow) * K + skc;
  size_t half = (size_t)64 * K;
  f32x4 acc[4][4];
#pragma unroll
  for (int i = 0; i < 4; ++i)
#pragma unroll
    for (int j = 0; j < 4; ++j) acc[i][j] = (f32x4){0.f, 0.f, 0.f, 0.f};
  int sAo = srow * 32 + skc;
  for (int k0 = 0; k0 < K; k0 += 32) {
    __syncthreads();
    gl16(pAh, &AsH[sAo]); gl16(pAh + half, &AsH[sAo + 64*32]);
    gl16(pAl, &AsL[sAo]); gl16(pAl + half, &AsL[sAo + 64*32]);
    gl16(pBh, &BsH[sAo]); gl16(pBh + half, &BsH[sAo + 64*32]);
    gl16(pBl, &BsL[sAo]); gl16(pBl + half, &BsL[sAo + 64*32]);
    pAh += 32; pAl += 32; pBh += 32; pBl += 32;
    __syncthreads();
    bf16x8 ah[4], al[4], bh[4], bl[4];
#pragma unroll
    for (int i = 0; i < 4; ++i) {
      int ar = (wr*64 + i*16 + lr) * 32 + lk*8;
      int br = (wc*64 + i*16 + lr) * 32 + lk*8;
      ah[i] = *(const bf16x8*)&AsH[ar];
      al[i] = *(const bf16x8*)&AsL[ar];
      bh[i] = *(const bf16x8*)&BsH[br];
      bl[i] = *(const bf16x8*)&BsL[br];
    }
#pragma unroll
    for (int mi = 0; mi < 4; ++mi)
#pragma unroll
      for (int ni = 0; ni < 4; ++ni) {
        acc[mi][ni] = __builtin_amdgcn_mfma_f32_16x16x32_bf16(ah[mi], bh[ni], acc[mi][ni], 0, 0, 0);
        acc[mi][ni] = __builtin_amdgcn_mfma_f32_16x16x32_bf16(ah[mi], bl[ni], acc[mi][ni], 0, 0, 0);
        acc[mi][ni] = __builtin_amdgcn_mfma_f32_16x16x32_bf16(al[mi], bh[ni], acc[mi][ni], 0, 0, 0);
      }
  }
#pragma unroll
  for (int mi = 0; mi < 4; ++mi) {
    int row0 = brow + wr*64 + mi*16 + lk*4;
#pragma unroll
    for (int ni = 0; ni < 4; ++ni) {
      int col = bcol + wc*64 + ni*16 + lr;
      float bv = bias ? bias[col] : 0.f;
#pragma unroll
      for (int r = 0; r < 4; ++r) {
        float v = acc[mi][ni][r] + bv;
        if (ACT == 1) v = 0.5f * v * (1.f + erff(v * 0.70710678118654752f));
        size_t idx = (size_t)(row0 + r) * Nc + col;
        if (SPLIT == 1) {
          unsigned short h = f2bf(v);
          Chi[idx] = h; Clo[idx] = f2bf(v - bf2f(h));
        } else if (SPLIT == 2) {
          Chi[idx] = f2bf(v);
        } else {
          C[idx] = v;
        }
      }
    }
  }
}

// ---------- copy h[:,0,:] to second output ----------
__global__ void k_copyh0(const float* __restrict__ h, float* __restrict__ o2) {
  int i = blockIdx.x * 256 + threadIdx.x;
  if (i < BB * DD) {
    int b = i / DD, d = i - b * DD;
    o2[i] = h[(size_t)(b * NN) * DD + d];
  }
}

extern "C" void kernel_launch(void* const* d_in, const int* in_sizes, int n_in,
                              void* d_out, int out_size, void* d_ws, size_t ws_size,
                              hipStream_t stream) {
  const float* tok_emb = (const float*)d_in[0];
  const float* emb_g  = (const float*)d_in[1];
  const float* emb_b  = (const float*)d_in[2];
  const float* n1_g   = (const float*)d_in[3];
  const float* n1_b   = (const float*)d_in[4];
  const float* n2_g   = (const float*)d_in[5];
  const float* n2_b   = (const float*)d_in[6];
  const float* qkv_w  = (const float*)d_in[7];
  const float* out_w  = (const float*)d_in[8];
  const float* ff_g   = (const float*)d_in[9];
  const float* ff_b   = (const float*)d_in[10];
  const float* ff_w1  = (const float*)d_in[11];
  const float* ff_b1  = (const float*)d_in[12];
  const float* ff_w2  = (const float*)d_in[13];
  const float* ff_b2  = (const float*)d_in[14];
  const float* h_w1   = (const float*)d_in[15];
  const float* h_b1   = (const float*)d_in[16];
  const float* h_g    = (const float*)d_in[17];
  const float* h_b    = (const float*)d_in[18];
  const float* h_w2   = (const float*)d_in[19];
  const float* h_b2   = (const float*)d_in[20];
  const int*   xi     = (const int*)d_in[21];
  float* outp = (float*)d_out;

  size_t szH  = (size_t)TT * DD;          // floats
  size_t szAM = (size_t)TT * MFF;         // ushorts per split act buffer
  size_t szQ  = (size_t)TT * 3 * DD;      // ushorts (qkv bf16)
  size_t szW  = (size_t)DD * VV;          // ushorts per split weight buffer

  char* p = (char*)d_ws;
  float* h   = (float*)p;                   p += szH * 4;
  float* t1  = (float*)p;                   p += szH * 4;
  float* t3  = (float*)p;                   p += szH * 4;
  unsigned short* t1b = (unsigned short*)p; p += szQ * 2;
  unsigned short* ahi = (unsigned short*)p; p += szAM * 2;
  unsigned short* alo = (unsigned short*)p; p += szAM * 2;
  unsigned short* bhi = (unsigned short*)p; p += szAM * 2;
  unsigned short* blo = (unsigned short*)p; p += szAM * 2;
  unsigned short* whi = (unsigned short*)p; p += szW * 2;
  unsigned short* wlo = (unsigned short*)p;

  k_embed_ln<<<TT, 256, 0, stream>>>(tok_emb, emb_g, emb_b, xi, h, ahi, alo);
  for (int l = 0; l < NLAYER; ++l) {
    k_wsplit<<<dim3(3*DD/64, DD/64), 256, 0, stream>>>(
        qkv_w + (size_t)l * DD * 3 * DD, whi, wlo, DD, 3*DD);
    k_mgemm<0,2><<<dim3(3*DD/128, TT/128), 256, 0, stream>>>(
        ahi, alo, whi, wlo, nullptr, nullptr, t1b, nullptr, DD, 3*DD);
    k_attn<<<BB * HH * (NN/64), 256, 0, stream>>>(t1b, xi, ahi, alo);
    k_wsplit<<<dim3(DD/64, DD/64), 256, 0, stream>>>(
        out_w + (size_t)l * DD * DD, whi, wlo, DD, DD);
    k_mgemm<0,0><<<dim3(DD/128, TT/128), 256, 0, stream>>>(
        ahi, alo, whi, wlo, nullptr, t3, nullptr, nullptr, DD, DD);
    k_ln2<<<TT, 256, 0, stream>>>(t3, h, n1_g, n1_b,
        ff_g + (size_t)l*DD, ff_b + (size_t)l*DD, h, ahi, alo);
    k_wsplit<<<dim3(MFF/64, DD/64), 256, 0, stream>>>(
        ff_w1 + (size_t)l * DD * MFF, whi, wlo, DD, MFF);
    k_mgemm<1,1><<<dim3(MFF/128, TT/128), 256, 0, stream>>>(
        ahi, alo, whi, wlo, ff_b1 + (size_t)l*MFF, nullptr, bhi, blo, DD, MFF);
    k_wsplit<<<dim3(DD/64, MFF/64), 256, 0, stream>>>(
        ff_w2 + (size_t)l * MFF * DD, whi, wlo, MFF, DD);
    k_mgemm<0,0><<<dim3(DD/128, TT/128), 256, 0, stream>>>(
        bhi, blo, whi, wlo, ff_b2 + (size_t)l*DD, t1, nullptr, nullptr, MFF, DD);
    k_ln<<<TT, 256, 0, stream>>>(t1, h, n2_g, n2_b, h, ahi, alo);
  }
  k_wsplit<<<dim3(DD/64, DD/64), 256, 0, stream>>>(h_w1, whi, wlo, DD, DD);
  k_mgemm<1,0><<<dim3(DD/128, TT/128), 256, 0, stream>>>(
      ahi, alo, whi, wlo, h_b1, t1, nullptr, nullptr, DD, DD);
  k_ln<<<TT, 256, 0, stream>>>(t1, nullptr, h_g, h_b, nullptr, ahi, alo);
  k_wsplit<<<dim3(VV/64, DD/64), 256, 0, stream>>>(h_w2, whi, wlo, DD, VV);
  k_mgemm<0,0><<<dim3(VV/128, TT/128), 256, 0, stream>>>(
      ahi, alo, whi, wlo, h_b2, outp, nullptr, nullptr, DD, VV);
  k_copyh0<<<(BB * DD + 255) / 256, 256, 0, stream>>>(h, outp + (size_t)TT * VV);
}

// Round 4
// 5621.555 us; speedup vs baseline: 2.7160x; 1.0334x over previous
//
#include <hip/hip_runtime.h>
#include <math.h>

#define DD 768
#define HH 12
#define DHH 64
#define NLAYER 12
#define MFF 3072
#define VV 32000
#define BB 8
#define NN 512
#define TT (BB*NN)

typedef __attribute__((ext_vector_type(8))) short bf16x8;
typedef __attribute__((ext_vector_type(4))) float f32x4;

// ---------- bf16 split helpers (RTNE) ----------
__device__ __forceinline__ unsigned short f2bf(float x) {
  unsigned u = __float_as_uint(x);
  unsigned r = u + 0x7FFFu + ((u >> 16) & 1u);
  return (unsigned short)(r >> 16);
}
__device__ __forceinline__ float bf2f(unsigned short h) {
  return __uint_as_float(((unsigned)h) << 16);
}

// ---------- async global->LDS 16B ----------
__device__ __forceinline__ void gl16(const void* g, void* l) {
  __builtin_amdgcn_global_load_lds(
      (const __attribute__((address_space(1))) unsigned*)g,
      (__attribute__((address_space(3))) unsigned*)l, 16, 0, 0);
}

// ---------- block-wide sum reduction of two values (256 threads = 4 waves) ----------
__device__ __forceinline__ void blockReduce2(float& a, float& b, float* sh) {
#pragma unroll
  for (int off = 32; off > 0; off >>= 1) {
    a += __shfl_down(a, off, 64);
    b += __shfl_down(b, off, 64);
  }
  int lane = threadIdx.x & 63;
  int w = threadIdx.x >> 6;
  if (lane == 0) { sh[2*w] = a; sh[2*w+1] = b; }
  __syncthreads();
  a = sh[0] + sh[2] + sh[4] + sh[6];
  b = sh[1] + sh[3] + sh[5] + sh[7];
}

// ---------- embedding gather + sinusoid PE + LayerNorm (+ bf16 split out) ----------
__global__ __launch_bounds__(256) void k_embed_ln(const float* __restrict__ emb,
    const float* __restrict__ g, const float* __restrict__ bb,
    const int* __restrict__ x, float* __restrict__ out,
    unsigned short* __restrict__ ohi, unsigned short* __restrict__ olo) {
  __shared__ float sh[8];
  int tok = blockIdx.x;
  int n = tok & (NN - 1);
  int t = x[tok];
  const float* row = emb + (size_t)t * DD;
  float v[3]; float s = 0.f, ss = 0.f;
#pragma unroll
  for (int i = 0; i < 3; ++i) {
    int d = threadIdx.x + 256 * i;
    int pair = d >> 1;
    float div = expf((float)(2 * pair) * (-9.210340371976184f / (float)DD));
    float ang = (float)n * div;
    float pe = (d & 1) ? cosf(ang) : sinf(ang);
    float val = row[d] + pe;
    v[i] = val; s += val; ss += val * val;
  }
  blockReduce2(s, ss, sh);
  float mu = s * (1.f / DD);
  float var = ss * (1.f / DD) - mu * mu;
  float rs = rsqrtf(var + 1e-5f);
#pragma unroll
  for (int i = 0; i < 3; ++i) {
    int d = threadIdx.x + 256 * i;
    float val = (v[i] - mu) * rs * g[d] + bb[d];
    size_t idx = (size_t)tok * DD + d;
    out[idx] = val;
    unsigned short h = f2bf(val); ohi[idx] = h; olo[idx] = f2bf(val - bf2f(h));
  }
}

// ---------- LayerNorm of (in0 [+ in1]) with optional fp32 / split outputs ----------
__global__ __launch_bounds__(256) void k_ln(const float* __restrict__ in0,
    const float* __restrict__ in1, const float* __restrict__ g,
    const float* __restrict__ bb, float* __restrict__ outf,
    unsigned short* __restrict__ ohi, unsigned short* __restrict__ olo) {
  __shared__ float sh[8];
  int tok = blockIdx.x;
  float v[3]; float s = 0.f, ss = 0.f;
#pragma unroll
  for (int i = 0; i < 3; ++i) {
    int d = threadIdx.x + 256 * i;
    float val = in0[(size_t)tok * DD + d];
    if (in1) val += in1[(size_t)tok * DD + d];
    v[i] = val; s += val; ss += val * val;
  }
  blockReduce2(s, ss, sh);
  float mu = s * (1.f / DD);
  float var = ss * (1.f / DD) - mu * mu;
  float rs = rsqrtf(var + 1e-5f);
#pragma unroll
  for (int i = 0; i < 3; ++i) {
    int d = threadIdx.x + 256 * i;
    float val = (v[i] - mu) * rs * g[d] + bb[d];
    size_t idx = (size_t)tok * DD + d;
    if (outf) outf[idx] = val;
    if (ohi) { unsigned short h = f2bf(val); ohi[idx] = h; olo[idx] = f2bf(val - bf2f(h)); }
  }
}

// ---------- fused: y1 = LN(in0+res)*g1+b1 -> outf;  y2 = LN(y1)*g2+b2 -> split ----------
__global__ __launch_bounds__(256) void k_ln2(const float* __restrict__ in0,
    const float* __restrict__ res, const float* __restrict__ g1,
    const float* __restrict__ b1v, const float* __restrict__ g2,
    const float* __restrict__ b2v, float* __restrict__ outf,
    unsigned short* __restrict__ ohi, unsigned short* __restrict__ olo) {
  __shared__ float sh[8];
  int tok = blockIdx.x;
  float v[3]; float s = 0.f, ss = 0.f;
#pragma unroll
  for (int i = 0; i < 3; ++i) {
    int d = threadIdx.x + 256 * i;
    float val = in0[(size_t)tok * DD + d] + res[(size_t)tok * DD + d];
    v[i] = val; s += val; ss += val * val;
  }
  blockReduce2(s, ss, sh);
  float mu = s * (1.f / DD);
  float var = ss * (1.f / DD) - mu * mu;
  float rs = rsqrtf(var + 1e-5f);
  float y[3]; float s2 = 0.f, ss2 = 0.f;
#pragma unroll
  for (int i = 0; i < 3; ++i) {
    int d = threadIdx.x + 256 * i;
    float yy = (v[i] - mu) * rs * g1[d] + b1v[d];
    y[i] = yy; s2 += yy; ss2 += yy * yy;
    outf[(size_t)tok * DD + d] = yy;
  }
  __syncthreads();   // sh reuse
  blockReduce2(s2, ss2, sh);
  float mu2 = s2 * (1.f / DD);
  float var2 = ss2 * (1.f / DD) - mu2 * mu2;
  float rs2 = rsqrtf(var2 + 1e-5f);
#pragma unroll
  for (int i = 0; i < 3; ++i) {
    int d = threadIdx.x + 256 * i;
    float val = (y[i] - mu2) * rs2 * g2[d] + b2v[d];
    size_t idx = (size_t)tok * DD + d;
    unsigned short h = f2bf(val); ohi[idx] = h; olo[idx] = f2bf(val - bf2f(h));
  }
}

// ---------- RoPE on 8 packed bf16 (4 pairs), pair base pbase ----------
__device__ __forceinline__ void rope8(bf16x8& v, int pbase, float npos) {
#pragma unroll
  for (int i = 0; i < 4; ++i) {
    float inv = expf(-0.57564627324851148f * (float)(pbase + i)); // 10000^(-p/16)
    float ang = npos * inv;
    float sn, cs;
    __sincosf(ang, &sn, &cs);
    float x0 = bf2f((unsigned short)v[2*i]);
    float x1 = bf2f((unsigned short)v[2*i+1]);
    v[2*i]   = (short)f2bf(x0 * cs - x1 * sn);
    v[2*i+1] = (short)f2bf(x1 * cs + x0 * sn);
  }
}

// ---------- MFMA flash attention: block = 64 q rows of one (b,h), 4 waves x 16 rows ----------
__global__ __launch_bounds__(256) void k_attn(const unsigned short* __restrict__ qkvb,
    const int* __restrict__ x,
    unsigned short* __restrict__ ohi, unsigned short* __restrict__ olo) {
  __shared__ unsigned short Ks[64][72];      // K[key][d]
  __shared__ unsigned short Vt[64][72];      // V^T[d][key]
  __shared__ unsigned short Ps[4][16][72];   // per-wave P[q][key]
  __shared__ float maskv[64];
  // XCD swizzle: 8 q-blocks sharing one (b,h)'s K/V land on one XCD's L2
  int nblk = gridDim.x;
  int bid = blockIdx.x;
  int blk = (bid & 7) * (nblk >> 3) + (bid >> 3);
  int qb = blk & 7;
  int hh = (blk >> 3) % HH;
  int b = blk / (8 * HH);
  int q0 = qb * 64;
  int tid = threadIdx.x;
  int w = tid >> 6, l = tid & 63;
  int g = l >> 4, c = l & 15;

  bf16x8 qa0, qa1;
  {
    int q = q0 + 16 * w + c;
    const unsigned short* qp = qkvb + (size_t)(b * NN + q) * (3 * DD) + hh * DHH;
    qa0 = *(const bf16x8*)(qp + 8 * g);
    qa1 = *(const bf16x8*)(qp + 32 + 8 * g);
    rope8(qa0, 4 * g, (float)q);
  }
  f32x4 o[4];
#pragma unroll
  for (int f = 0; f < 4; ++f) o[f] = (f32x4){0.f,0.f,0.f,0.f};
  float m_run[4] = {-INFINITY,-INFINITY,-INFINITY,-INFINITY};
  float l_run[4] = {0.f,0.f,0.f,0.f};

  int kr = tid >> 2;
  int kd = (tid & 3) * 16;
  for (int kt = 0; kt < NN; kt += 64) {
    __syncthreads();
    {
      int tok = b * NN + kt + kr;
      const unsigned short* kp = qkvb + (size_t)tok * (3 * DD) + DD + hh * DHH + kd;
      const unsigned short* vp = kp + DD;
      bf16x8 k0 = *(const bf16x8*)kp;
      bf16x8 k1 = *(const bf16x8*)(kp + 8);
      if (kd < 32) {
        float npos = (float)(kt + kr);
        rope8(k0, kd / 2, npos);
        rope8(k1, kd / 2 + 4, npos);
      }
      *(bf16x8*)&Ks[kr][kd] = k0;
      *(bf16x8*)&Ks[kr][kd + 8] = k1;
      bf16x8 v0 = *(const bf16x8*)vp;
      bf16x8 v1 = *(const bf16x8*)(vp + 8);
#pragma unroll
      for (int j = 0; j < 8; ++j) {
        Vt[kd + j][kr] = (unsigned short)v0[j];
        Vt[kd + 8 + j][kr] = (unsigned short)v1[j];
      }
    }
    if (tid < 64) maskv[tid] = (x[b * NN + kt + tid] == 0) ? 1.f : 0.f;
    __syncthreads();

    f32x4 sc[4];
#pragma unroll
    for (int f = 0; f < 4; ++f) {
      bf16x8 kb0 = *(const bf16x8*)&Ks[16 * f + c][8 * g];
      bf16x8 kb1 = *(const bf16x8*)&Ks[16 * f + c][32 + 8 * g];
      f32x4 sacc = (f32x4){0.f,0.f,0.f,0.f};
      sacc = __builtin_amdgcn_mfma_f32_16x16x32_bf16(qa0, kb0, sacc, 0, 0, 0);
      sacc = __builtin_amdgcn_mfma_f32_16x16x32_bf16(qa1, kb1, sacc, 0, 0, 0);
      float mk = maskv[16 * f + c];
#pragma unroll
      for (int r = 0; r < 4; ++r) {
        float sv = sacc[r] * 0.125f;
        sacc[r] = (mk != 0.f) ? 1e-9f : sv;
      }
      sc[f] = sacc;
    }
    float fs[4];
#pragma unroll
    for (int r = 0; r < 4; ++r) {
      float m = fmaxf(fmaxf(sc[0][r], sc[1][r]), fmaxf(sc[2][r], sc[3][r]));
      m = fmaxf(m, __shfl_xor(m, 1, 64));
      m = fmaxf(m, __shfl_xor(m, 2, 64));
      m = fmaxf(m, __shfl_xor(m, 4, 64));
      m = fmaxf(m, __shfl_xor(m, 8, 64));
      float mn = fmaxf(m_run[r], m);
      fs[r] = expf(m_run[r] - mn);
      m_run[r] = mn;
    }
    float tsum[4] = {0.f,0.f,0.f,0.f};
#pragma unroll
    for (int f = 0; f < 4; ++f)
#pragma unroll
      for (int r = 0; r < 4; ++r) {
        float p = expf(sc[f][r] - m_run[r]);
        Ps[w][4 * g + r][16 * f + c] = f2bf(p);
        tsum[r] += p;
      }
#pragma unroll
    for (int r = 0; r < 4; ++r) {
      float t = tsum[r];
      t += __shfl_xor(t, 1, 64);
      t += __shfl_xor(t, 2, 64);
      t += __shfl_xor(t, 4, 64);
      t += __shfl_xor(t, 8, 64);
      l_run[r] = l_run[r] * fs[r] + t;
#pragma unroll
      for (int f = 0; f < 4; ++f) o[f][r] *= fs[r];
    }
    asm volatile("s_waitcnt lgkmcnt(0)" ::: "memory");
    __builtin_amdgcn_sched_barrier(0);
    bf16x8 pa0 = *(const bf16x8*)&Ps[w][c][8 * g];
    bf16x8 pa1 = *(const bf16x8*)&Ps[w][c][32 + 8 * g];
#pragma unroll
    for (int f = 0; f < 4; ++f) {
      bf16x8 vb0 = *(const bf16x8*)&Vt[16 * f + c][8 * g];
      bf16x8 vb1 = *(const bf16x8*)&Vt[16 * f + c][32 + 8 * g];
      o[f] = __builtin_amdgcn_mfma_f32_16x16x32_bf16(pa0, vb0, o[f], 0, 0, 0);
      o[f] = __builtin_amdgcn_mfma_f32_16x16x32_bf16(pa1, vb1, o[f], 0, 0, 0);
    }
  }
#pragma unroll
  for (int r = 0; r < 4; ++r) {
    int tok = b * NN + q0 + 16 * w + 4 * g + r;
    float invl = 1.f / l_run[r];
#pragma unroll
    for (int f = 0; f < 4; ++f) {
      float vv = o[f][r] * invl;
      size_t idx = (size_t)tok * DD + hh * DHH + 16 * f + c;
      unsigned short h = f2bf(vv);
      ohi[idx] = h; olo[idx] = f2bf(vv - bf2f(h));
    }
  }
}

// ---------- weight transpose + bf16 hi/lo split: W[z][K][N] -> Wt{hi,lo}[z][N][K] ----------
__global__ __launch_bounds__(256) void k_wsplit(const float* __restrict__ W,
    unsigned short* __restrict__ Whi, unsigned short* __restrict__ Wlo, int K, int N) {
  __shared__ float tile[64][65];
  size_t zoff = (size_t)blockIdx.z * K * N;
  W += zoff; Whi += zoff; Wlo += zoff;
  int k0 = blockIdx.y * 64, n0 = blockIdx.x * 64;
  int tid = threadIdx.x;
#pragma unroll
  for (int it = 0; it < 4; ++it) {
    int r = (tid >> 4) + it * 16;
    int c = (tid & 15) * 4;
    float4 v = *(const float4*)&W[(size_t)(k0 + r) * N + n0 + c];
    tile[r][c] = v.x; tile[r][c+1] = v.y; tile[r][c+2] = v.z; tile[r][c+3] = v.w;
  }
  __syncthreads();
  int n = tid >> 2;
  int kb = (tid & 3) * 16;
  bf16x8 h0, h1, l0, l1;
#pragma unroll
  for (int i = 0; i < 8; ++i) {
    float xv = tile[kb + i][n];
    unsigned short h = f2bf(xv);
    h0[i] = (short)h; l0[i] = (short)f2bf(xv - bf2f(h));
  }
#pragma unroll
  for (int i = 0; i < 8; ++i) {
    float xv = tile[kb + 8 + i][n];
    unsigned short h = f2bf(xv);
    h1[i] = (short)h; l1[i] = (short)f2bf(xv - bf2f(h));
  }
  size_t ob = (size_t)(n0 + n) * K + k0 + kb;
  *(bf16x8*)&Whi[ob] = h0; *(bf16x8*)&Whi[ob + 8] = h1;
  *(bf16x8*)&Wlo[ob] = l0; *(bf16x8*)&Wlo[ob + 8] = l1;
}

// ---------- split-bf16 MFMA GEMM: C[T x Nc] = A @ W ----------
// SPLIT: 0 = fp32 out, 1 = split hi/lo out, 2 = plain bf16 out (Chi). NT: nontemporal fp32 store.
// Block remap: XCD-bijective swizzle + N-chunks of CHX panels (full M per chunk).
template<int ACT, int SPLIT, int NT>
__global__ __launch_bounds__(256) void k_mgemm(
    const unsigned short* __restrict__ Ahi, const unsigned short* __restrict__ Alo,
    const unsigned short* __restrict__ Whi, const unsigned short* __restrict__ Wlo,
    const float* __restrict__ bias, float* __restrict__ C,
    unsigned short* __restrict__ Chi, unsigned short* __restrict__ Clo,
    int K, int Nc, int CHX) {
  __shared__ unsigned short AsH[128*32], AsL[128*32], BsH[128*32], BsL[128*32];
  int nbx = gridDim.x, nby = gridDim.y;
  int bid = blockIdx.y * nbx + blockIdx.x;
  int nwg = nbx * nby;                      // always % 8 == 0 here
  int sw = (bid & 7) * (nwg >> 3) + (bid >> 3);
  int per = CHX * nby;
  int st = sw / per, off = sw - st * per;
  int bx = st * CHX + (off % CHX);
  int by = off / CHX;
  int brow = by * 128, bcol = bx * 128;
  int tid = threadIdx.x;
  int w = tid >> 6, l = tid & 63;
  int wr = w >> 1, wc = w & 1;
  int lr = l & 15;
  int lk = l >> 4;
  int srow = w * 16 + (l >> 2);
  int skc = (l & 3) * 8;
  const unsigned short* pAh = Ahi + (size_t)(brow + srow) * K + skc;
  const unsigned short* pAl = Alo + (size_t)(brow + srow) * K + skc;
  const unsigned short* pBh = Whi + (size_t)(bcol + srow) * K + skc;
  const unsigned short* pBl = Wlo + (size_t)(bcol + srow) * K + skc;
  size_t half = (size_t)64 * K;
  f32x4 acc[4][4];
#pragma unroll
  for (int i = 0; i < 4; ++i)
#pragma unroll
    for (int j = 0; j < 4; ++j) acc[i][j] = (f32x4){0.f, 0.f, 0.f, 0.f};
  int sAo = srow * 32 + skc;
  for (int k0 = 0; k0 < K; k0 += 32) {
    __syncthreads();
    gl16(pAh, &AsH[sAo]); gl16(pAh + half, &AsH[sAo + 64*32]);
    gl16(pAl, &AsL[sAo]); gl16(pAl + half, &AsL[sAo + 64*32]);
    gl16(pBh, &BsH[sAo]); gl16(pBh + half, &BsH[sAo + 64*32]);
    gl16(pBl, &BsL[sAo]); gl16(pBl + half, &BsL[sAo + 64*32]);
    pAh += 32; pAl += 32; pBh += 32; pBl += 32;
    __syncthreads();
    bf16x8 ah[4], al[4], bh[4], bl[4];
#pragma unroll
    for (int i = 0; i < 4; ++i) {
      int ar = (wr*64 + i*16 + lr) * 32 + lk*8;
      int br = (wc*64 + i*16 + lr) * 32 + lk*8;
      ah[i] = *(const bf16x8*)&AsH[ar];
      al[i] = *(const bf16x8*)&AsL[ar];
      bh[i] = *(const bf16x8*)&BsH[br];
      bl[i] = *(const bf16x8*)&BsL[br];
    }
#pragma unroll
    for (int mi = 0; mi < 4; ++mi)
#pragma unroll
      for (int ni = 0; ni < 4; ++ni) {
        acc[mi][ni] = __builtin_amdgcn_mfma_f32_16x16x32_bf16(ah[mi], bh[ni], acc[mi][ni], 0, 0, 0);
        acc[mi][ni] = __builtin_amdgcn_mfma_f32_16x16x32_bf16(ah[mi], bl[ni], acc[mi][ni], 0, 0, 0);
        acc[mi][ni] = __builtin_amdgcn_mfma_f32_16x16x32_bf16(al[mi], bh[ni], acc[mi][ni], 0, 0, 0);
      }
  }
#pragma unroll
  for (int mi = 0; mi < 4; ++mi) {
    int row0 = brow + wr*64 + mi*16 + lk*4;
#pragma unroll
    for (int ni = 0; ni < 4; ++ni) {
      int col = bcol + wc*64 + ni*16 + lr;
      float bv = bias ? bias[col] : 0.f;
#pragma unroll
      for (int r = 0; r < 4; ++r) {
        float v = acc[mi][ni][r] + bv;
        if (ACT == 1) v = 0.5f * v * (1.f + erff(v * 0.70710678118654752f));
        size_t idx = (size_t)(row0 + r) * Nc + col;
        if (SPLIT == 1) {
          unsigned short h = f2bf(v);
          Chi[idx] = h; Clo[idx] = f2bf(v - bf2f(h));
        } else if (SPLIT == 2) {
          Chi[idx] = f2bf(v);
        } else {
          if (NT) __builtin_nontemporal_store(v, &C[idx]);
          else C[idx] = v;
        }
      }
    }
  }
}

// ---------- copy h[:,0,:] to second output ----------
__global__ void k_copyh0(const float* __restrict__ h, float* __restrict__ o2) {
  int i = blockIdx.x * 256 + threadIdx.x;
  if (i < BB * DD) {
    int b = i / DD, d = i - b * DD;
    o2[i] = h[(size_t)(b * NN) * DD + d];
  }
}

extern "C" void kernel_launch(void* const* d_in, const int* in_sizes, int n_in,
                              void* d_out, int out_size, void* d_ws, size_t ws_size,
                              hipStream_t stream) {
  const float* tok_emb = (const float*)d_in[0];
  const float* emb_g  = (const float*)d_in[1];
  const float* emb_b  = (const float*)d_in[2];
  const float* n1_g   = (const float*)d_in[3];
  const float* n1_b   = (const float*)d_in[4];
  const float* n2_g   = (const float*)d_in[5];
  const float* n2_b   = (const float*)d_in[6];
  const float* qkv_w  = (const float*)d_in[7];
  const float* out_w  = (const float*)d_in[8];
  const float* ff_g   = (const float*)d_in[9];
  const float* ff_b   = (const float*)d_in[10];
  const float* ff_w1  = (const float*)d_in[11];
  const float* ff_b1  = (const float*)d_in[12];
  const float* ff_w2  = (const float*)d_in[13];
  const float* ff_b2  = (const float*)d_in[14];
  const float* h_w1   = (const float*)d_in[15];
  const float* h_b1   = (const float*)d_in[16];
  const float* h_g    = (const float*)d_in[17];
  const float* h_b    = (const float*)d_in[18];
  const float* h_w2   = (const float*)d_in[19];
  const float* h_b2   = (const float*)d_in[20];
  const int*   xi     = (const int*)d_in[21];
  float* outp = (float*)d_out;

  size_t szH  = (size_t)TT * DD;          // floats
  size_t szAM = (size_t)TT * MFF;         // ushorts per split act buffer
  size_t szQ  = (size_t)TT * 3 * DD;      // ushorts (qkv bf16)
  size_t szW  = (size_t)DD * VV;          // ushorts per shared split weight buffer

  // per-weight-group element counts (for full pre-split path)
  size_t eQKV = (size_t)NLAYER * DD * 3 * DD;
  size_t eOUT = (size_t)NLAYER * DD * DD;
  size_t eFF1 = (size_t)NLAYER * DD * MFF;
  size_t eFF2 = (size_t)NLAYER * MFF * DD;
  size_t eHW1 = (size_t)DD * DD;
  size_t eLG  = (size_t)DD * VV;
  size_t eWT  = eQKV + eOUT + eFF1 + eFF2 + eHW1 + eLG;

  size_t actBytes = szH*4*3 + szQ*2 + szAM*2*4;
  size_t needFull = actBytes + eWT * 2 * 2;          // hi+lo, 2B each
  size_t needBase = actBytes + szW * 2 * 2;

  char* p = (char*)d_ws;
  float* h   = (float*)p;                   p += szH * 4;
  float* t1  = (float*)p;                   p += szH * 4;
  float* t3  = (float*)p;                   p += szH * 4;
  unsigned short* t1b = (unsigned short*)p; p += szQ * 2;
  unsigned short* ahi = (unsigned short*)p; p += szAM * 2;
  unsigned short* alo = (unsigned short*)p; p += szAM * 2;
  unsigned short* bhi = (unsigned short*)p; p += szAM * 2;
  unsigned short* blo = (unsigned short*)p; p += szAM * 2;

  bool full = (ws_size >= needFull);
  // weight pointers (hi followed by lo per group in full mode; shared buffer otherwise)
  unsigned short *qkvh, *qkvl, *outh, *outl, *f1h, *f1l, *f2h, *f2l, *hw1h, *hw1l, *lgh, *lgl;
  unsigned short *whi = nullptr, *wlo = nullptr;
  if (full) {
    qkvh = (unsigned short*)p; p += eQKV * 2; qkvl = (unsigned short*)p; p += eQKV * 2;
    outh = (unsigned short*)p; p += eOUT * 2; outl = (unsigned short*)p; p += eOUT * 2;
    f1h  = (unsigned short*)p; p += eFF1 * 2; f1l  = (unsigned short*)p; p += eFF1 * 2;
    f2h  = (unsigned short*)p; p += eFF2 * 2; f2l  = (unsigned short*)p; p += eFF2 * 2;
    hw1h = (unsigned short*)p; p += eHW1 * 2; hw1l = (unsigned short*)p; p += eHW1 * 2;
    lgh  = (unsigned short*)p; p += eLG * 2;  lgl  = (unsigned short*)p;
    // batched pre-split of ALL weights (z = layer)
    k_wsplit<<<dim3(3*DD/64, DD/64, NLAYER), 256, 0, stream>>>(qkv_w, qkvh, qkvl, DD, 3*DD);
    k_wsplit<<<dim3(DD/64, DD/64, NLAYER), 256, 0, stream>>>(out_w, outh, outl, DD, DD);
    k_wsplit<<<dim3(MFF/64, DD/64, NLAYER), 256, 0, stream>>>(ff_w1, f1h, f1l, DD, MFF);
    k_wsplit<<<dim3(DD/64, MFF/64, NLAYER), 256, 0, stream>>>(ff_w2, f2h, f2l, MFF, DD);
    k_wsplit<<<dim3(DD/64, DD/64, 1), 256, 0, stream>>>(h_w1, hw1h, hw1l, DD, DD);
    k_wsplit<<<dim3(VV/64, DD/64, 1), 256, 0, stream>>>(h_w2, lgh, lgl, DD, VV);
  } else {
    whi = (unsigned short*)p; p += szW * 2;
    wlo = (unsigned short*)p;
  }

  k_embed_ln<<<TT, 256, 0, stream>>>(tok_emb, emb_g, emb_b, xi, h, ahi, alo);
  for (int l = 0; l < NLAYER; ++l) {
    const unsigned short *wh, *wl;
    // ---- qkv ----
    if (full) { wh = qkvh + (size_t)l * DD * 3 * DD; wl = qkvl + (size_t)l * DD * 3 * DD; }
    else {
      k_wsplit<<<dim3(3*DD/64, DD/64, 1), 256, 0, stream>>>(
          qkv_w + (size_t)l * DD * 3 * DD, whi, wlo, DD, 3*DD);
      wh = whi; wl = wlo;
    }
    k_mgemm<0,2,0><<<dim3(3*DD/128, TT/128), 256, 0, stream>>>(
        ahi, alo, wh, wl, nullptr, nullptr, t1b, nullptr, DD, 3*DD, 6);
    k_attn<<<BB * HH * (NN/64), 256, 0, stream>>>(t1b, xi, ahi, alo);
    // ---- attn out ----
    if (full) { wh = outh + (size_t)l * DD * DD; wl = outl + (size_t)l * DD * DD; }
    else {
      k_wsplit<<<dim3(DD/64, DD/64, 1), 256, 0, stream>>>(
          out_w + (size_t)l * DD * DD, whi, wlo, DD, DD);
      wh = whi; wl = wlo;
    }
    k_mgemm<0,0,0><<<dim3(DD/128, TT/128), 256, 0, stream>>>(
        ahi, alo, wh, wl, nullptr, t3, nullptr, nullptr, DD, DD, 6);
    k_ln2<<<TT, 256, 0, stream>>>(t3, h, n1_g, n1_b,
        ff_g + (size_t)l*DD, ff_b + (size_t)l*DD, h, ahi, alo);
    // ---- ff1 ----
    if (full) { wh = f1h + (size_t)l * DD * MFF; wl = f1l + (size_t)l * DD * MFF; }
    else {
      k_wsplit<<<dim3(MFF/64, DD/64, 1), 256, 0, stream>>>(
          ff_w1 + (size_t)l * DD * MFF, whi, wlo, DD, MFF);
      wh = whi; wl = wlo;
    }
    k_mgemm<1,1,0><<<dim3(MFF/128, TT/128), 256, 0, stream>>>(
        ahi, alo, wh, wl, ff_b1 + (size_t)l*MFF, nullptr, bhi, blo, DD, MFF, 8);
    // ---- ff2 ----
    if (full) { wh = f2h + (size_t)l * MFF * DD; wl = f2l + (size_t)l * MFF * DD; }
    else {
      k_wsplit<<<dim3(DD/64, MFF/64, 1), 256, 0, stream>>>(
          ff_w2 + (size_t)l * MFF * DD, whi, wlo, MFF, DD);
      wh = whi; wl = wlo;
    }
    k_mgemm<0,0,0><<<dim3(DD/128, TT/128), 256, 0, stream>>>(
        bhi, blo, wh, wl, ff_b2 + (size_t)l*DD, t1, nullptr, nullptr, MFF, DD, 6);
    k_ln<<<TT, 256, 0, stream>>>(t1, h, n2_g, n2_b, h, ahi, alo);
  }
  // ---- head ----
  {
    const unsigned short *wh, *wl;
    if (full) { wh = hw1h; wl = hw1l; }
    else {
      k_wsplit<<<dim3(DD/64, DD/64, 1), 256, 0, stream>>>(h_w1, whi, wlo, DD, DD);
      wh = whi; wl = wlo;
    }
    k_mgemm<1,0,0><<<dim3(DD/128, TT/128), 256, 0, stream>>>(
        ahi, alo, wh, wl, h_b1, t1, nullptr, nullptr, DD, DD, 6);
    k_ln<<<TT, 256, 0, stream>>>(t1, nullptr, h_g, h_b, nullptr, ahi, alo);
    if (full) { wh = lgh; wl = lgl; }
    else {
      k_wsplit<<<dim3(VV/64, DD/64, 1), 256, 0, stream>>>(h_w2, whi, wlo, DD, VV);
      wh = whi; wl = wlo;
    }
    k_mgemm<0,0,1><<<dim3(VV/128, TT/128), 256, 0, stream>>>(
        ahi, alo, wh, wl, h_b2, outp, nullptr, nullptr, DD, VV, 10);
  }
  k_copyh0<<<(BB * DD + 255) / 256, 256, 0, stream>>>(h, outp + (size_t)TT * VV);
}

// Round 5
// 5137.767 us; speedup vs baseline: 2.9718x; 1.0942x over previous
//
#include <hip/hip_runtime.h>
#include <math.h>

#define DD 768
#define HH 12
#define DHH 64
#define NLAYER 12
#define MFF 3072
#define VV 32000
#define BB 8
#define NN 512
#define TT (BB*NN)

typedef __attribute__((ext_vector_type(8))) short bf16x8;
typedef __attribute__((ext_vector_type(4))) float f32x4;

// ---------- bf16 split helpers (RTNE) ----------
__device__ __forceinline__ unsigned short f2bf(float x) {
  unsigned u = __float_as_uint(x);
  unsigned r = u + 0x7FFFu + ((u >> 16) & 1u);
  return (unsigned short)(r >> 16);
}
__device__ __forceinline__ float bf2f(unsigned short h) {
  return __uint_as_float(((unsigned)h) << 16);
}

// ---------- async global->LDS 16B ----------
__device__ __forceinline__ void gl16(const void* g, void* l) {
  __builtin_amdgcn_global_load_lds(
      (const __attribute__((address_space(1))) unsigned*)g,
      (__attribute__((address_space(3))) unsigned*)l, 16, 0, 0);
}

// ---------- block-wide sum reduction of two values (256 threads = 4 waves) ----------
__device__ __forceinline__ void blockReduce2(float& a, float& b, float* sh) {
#pragma unroll
  for (int off = 32; off > 0; off >>= 1) {
    a += __shfl_down(a, off, 64);
    b += __shfl_down(b, off, 64);
  }
  int lane = threadIdx.x & 63;
  int w = threadIdx.x >> 6;
  if (lane == 0) { sh[2*w] = a; sh[2*w+1] = b; }
  __syncthreads();
  a = sh[0] + sh[2] + sh[4] + sh[6];
  b = sh[1] + sh[3] + sh[5] + sh[7];
}

// ---------- rope cos/sin tables: [NN][16] ----------
__global__ void k_ropetab(float* __restrict__ rc, float* __restrict__ rsn) {
  int i = blockIdx.x * 256 + threadIdx.x;
  if (i < NN * 16) {
    int pos = i >> 4, pr = i & 15;
    float inv = expf(-0.57564627324851148f * (float)pr);  // 10000^(-pr/16)
    float ang = (float)pos * inv;
    rc[i] = cosf(ang); rsn[i] = sinf(ang);
  }
}

// ---------- embedding gather + sinusoid PE + LayerNorm (+ bf16 split out) ----------
__global__ __launch_bounds__(256) void k_embed_ln(const float* __restrict__ emb,
    const float* __restrict__ g, const float* __restrict__ bb,
    const int* __restrict__ x, float* __restrict__ out,
    unsigned short* __restrict__ ohi, unsigned short* __restrict__ olo) {
  __shared__ float sh[8];
  int tok = blockIdx.x;
  int n = tok & (NN - 1);
  int t = x[tok];
  const float* row = emb + (size_t)t * DD;
  float v[3]; float s = 0.f, ss = 0.f;
#pragma unroll
  for (int i = 0; i < 3; ++i) {
    int d = threadIdx.x + 256 * i;
    int pair = d >> 1;
    float div = expf((float)(2 * pair) * (-9.210340371976184f / (float)DD));
    float ang = (float)n * div;
    float pe = (d & 1) ? cosf(ang) : sinf(ang);
    float val = row[d] + pe;
    v[i] = val; s += val; ss += val * val;
  }
  blockReduce2(s, ss, sh);
  float mu = s * (1.f / DD);
  float var = ss * (1.f / DD) - mu * mu;
  float rs = rsqrtf(var + 1e-5f);
#pragma unroll
  for (int i = 0; i < 3; ++i) {
    int d = threadIdx.x + 256 * i;
    float val = (v[i] - mu) * rs * g[d] + bb[d];
    size_t idx = (size_t)tok * DD + d;
    out[idx] = val;
    unsigned short h = f2bf(val); ohi[idx] = h; olo[idx] = f2bf(val - bf2f(h));
  }
}

// ---------- fused reducer + LayerNorm(s) ----------
// val = p0 [+ p1] [+ bias] [+ res]; [GELU]; y1 = LN(val)*g1+b1
// LN2==0: outf?=y1, split(y1).   LN2==1: outf=y1, y2=LN(y1)*g2+b2, split(y2).
template<int NP, int GELU, int LN2>
__global__ __launch_bounds__(256) void k_lnS(
    const float* __restrict__ p0, const float* __restrict__ p1,
    const float* __restrict__ bias, const float* __restrict__ res,
    const float* __restrict__ g1, const float* __restrict__ b1v,
    const float* __restrict__ g2, const float* __restrict__ b2v,
    float* __restrict__ outf,
    unsigned short* __restrict__ ohi, unsigned short* __restrict__ olo) {
  __shared__ float sh[8];
  int tok = blockIdx.x;
  float v[3]; float s = 0.f, ss = 0.f;
#pragma unroll
  for (int i = 0; i < 3; ++i) {
    int d = threadIdx.x + 256 * i;
    size_t idx = (size_t)tok * DD + d;
    float val = p0[idx];
    if (NP > 1) val += p1[idx];
    if (bias) val += bias[d];
    if (res) val += res[idx];
    if (GELU) val = 0.5f * val * (1.f + erff(val * 0.70710678118654752f));
    v[i] = val; s += val; ss += val * val;
  }
  blockReduce2(s, ss, sh);
  float mu = s * (1.f / DD);
  float var = ss * (1.f / DD) - mu * mu;
  float rs = rsqrtf(var + 1e-5f);
  if (LN2) {
    float y[3]; float s2 = 0.f, ss2 = 0.f;
#pragma unroll
    for (int i = 0; i < 3; ++i) {
      int d = threadIdx.x + 256 * i;
      float yy = (v[i] - mu) * rs * g1[d] + b1v[d];
      y[i] = yy; s2 += yy; ss2 += yy * yy;
      outf[(size_t)tok * DD + d] = yy;
    }
    __syncthreads();
    blockReduce2(s2, ss2, sh);
    float mu2 = s2 * (1.f / DD);
    float var2 = ss2 * (1.f / DD) - mu2 * mu2;
    float rs2 = rsqrtf(var2 + 1e-5f);
#pragma unroll
    for (int i = 0; i < 3; ++i) {
      int d = threadIdx.x + 256 * i;
      float val = (y[i] - mu2) * rs2 * g2[d] + b2v[d];
      size_t idx = (size_t)tok * DD + d;
      unsigned short h = f2bf(val); ohi[idx] = h; olo[idx] = f2bf(val - bf2f(h));
    }
  } else {
#pragma unroll
    for (int i = 0; i < 3; ++i) {
      int d = threadIdx.x + 256 * i;
      float val = (v[i] - mu) * rs * g1[d] + b1v[d];
      size_t idx = (size_t)tok * DD + d;
      if (outf) outf[idx] = val;
      unsigned short h = f2bf(val); ohi[idx] = h; olo[idx] = f2bf(val - bf2f(h));
    }
  }
}

// ---------- RoPE on 8 packed bf16 (4 pairs) via table, base = pos*16 + pair0 ----------
__device__ __forceinline__ void rope8t(bf16x8& v, const float* __restrict__ rc,
    const float* __restrict__ rsn, int base) {
#pragma unroll
  for (int i = 0; i < 4; ++i) {
    float cs = rc[base + i];
    float sn = rsn[base + i];
    float x0 = bf2f((unsigned short)v[2*i]);
    float x1 = bf2f((unsigned short)v[2*i+1]);
    v[2*i]   = (short)f2bf(x0 * cs - x1 * sn);
    v[2*i+1] = (short)f2bf(x1 * cs + x0 * sn);
  }
}

// ---------- MFMA flash attention: block = 64 q rows of one (b,h), 4 waves x 16 rows ----------
__global__ __launch_bounds__(256) void k_attn(const unsigned short* __restrict__ qkvb,
    const int* __restrict__ x, const float* __restrict__ rc, const float* __restrict__ rsn,
    unsigned short* __restrict__ ohi, unsigned short* __restrict__ olo) {
  __shared__ unsigned short Ks[64][72];      // K[key][d]
  __shared__ unsigned short Vt[64][72];      // V^T[d][key]
  __shared__ unsigned short Ps[4][16][72];   // per-wave P[q][key]
  __shared__ float maskv[64];
  int nblk = gridDim.x;
  int bid = blockIdx.x;
  int blk = (bid & 7) * (nblk >> 3) + (bid >> 3);
  int qb = blk & 7;
  int hh = (blk >> 3) % HH;
  int b = blk / (8 * HH);
  int q0 = qb * 64;
  int tid = threadIdx.x;
  int w = tid >> 6, l = tid & 63;
  int g = l >> 4, c = l & 15;

  bf16x8 qa0, qa1;
  {
    int q = q0 + 16 * w + c;
    const unsigned short* qp = qkvb + (size_t)(b * NN + q) * (3 * DD) + hh * DHH;
    qa0 = *(const bf16x8*)(qp + 8 * g);
    qa1 = *(const bf16x8*)(qp + 32 + 8 * g);
    rope8t(qa0, rc, rsn, q * 16 + 4 * g);
  }
  f32x4 o[4];
#pragma unroll
  for (int f = 0; f < 4; ++f) o[f] = (f32x4){0.f,0.f,0.f,0.f};
  float m_run[4] = {-INFINITY,-INFINITY,-INFINITY,-INFINITY};
  float l_run[4] = {0.f,0.f,0.f,0.f};

  int kr = tid >> 2;
  int kd = (tid & 3) * 16;
  for (int kt = 0; kt < NN; kt += 64) {
    __syncthreads();
    {
      int tok = b * NN + kt + kr;
      const unsigned short* kp = qkvb + (size_t)tok * (3 * DD) + DD + hh * DHH + kd;
      const unsigned short* vp = kp + DD;
      bf16x8 k0 = *(const bf16x8*)kp;
      bf16x8 k1 = *(const bf16x8*)(kp + 8);
      if (kd < 32) {
        int base = (kt + kr) * 16 + kd / 2;
        rope8t(k0, rc, rsn, base);
        rope8t(k1, rc, rsn, base + 4);
      }
      *(bf16x8*)&Ks[kr][kd] = k0;
      *(bf16x8*)&Ks[kr][kd + 8] = k1;
      bf16x8 v0 = *(const bf16x8*)vp;
      bf16x8 v1 = *(const bf16x8*)(vp + 8);
#pragma unroll
      for (int j = 0; j < 8; ++j) {
        Vt[kd + j][kr] = (unsigned short)v0[j];
        Vt[kd + 8 + j][kr] = (unsigned short)v1[j];
      }
    }
    if (tid < 64) maskv[tid] = (x[b * NN + kt + tid] == 0) ? 1.f : 0.f;
    __syncthreads();

    f32x4 sc[4];
#pragma unroll
    for (int f = 0; f < 4; ++f) {
      bf16x8 kb0 = *(const bf16x8*)&Ks[16 * f + c][8 * g];
      bf16x8 kb1 = *(const bf16x8*)&Ks[16 * f + c][32 + 8 * g];
      f32x4 sacc = (f32x4){0.f,0.f,0.f,0.f};
      sacc = __builtin_amdgcn_mfma_f32_16x16x32_bf16(qa0, kb0, sacc, 0, 0, 0);
      sacc = __builtin_amdgcn_mfma_f32_16x16x32_bf16(qa1, kb1, sacc, 0, 0, 0);
      float mk = maskv[16 * f + c];
#pragma unroll
      for (int r = 0; r < 4; ++r) {
        float sv = sacc[r] * 0.125f;
        sacc[r] = (mk != 0.f) ? 1e-9f : sv;
      }
      sc[f] = sacc;
    }
    float fs[4];
#pragma unroll
    for (int r = 0; r < 4; ++r) {
      float m = fmaxf(fmaxf(sc[0][r], sc[1][r]), fmaxf(sc[2][r], sc[3][r]));
      m = fmaxf(m, __shfl_xor(m, 1, 64));
      m = fmaxf(m, __shfl_xor(m, 2, 64));
      m = fmaxf(m, __shfl_xor(m, 4, 64));
      m = fmaxf(m, __shfl_xor(m, 8, 64));
      float mn = fmaxf(m_run[r], m);
      fs[r] = expf(m_run[r] - mn);
      m_run[r] = mn;
    }
    float tsum[4] = {0.f,0.f,0.f,0.f};
#pragma unroll
    for (int f = 0; f < 4; ++f)
#pragma unroll
      for (int r = 0; r < 4; ++r) {
        float p = expf(sc[f][r] - m_run[r]);
        Ps[w][4 * g + r][16 * f + c] = f2bf(p);
        tsum[r] += p;
      }
#pragma unroll
    for (int r = 0; r < 4; ++r) {
      float t = tsum[r];
      t += __shfl_xor(t, 1, 64);
      t += __shfl_xor(t, 2, 64);
      t += __shfl_xor(t, 4, 64);
      t += __shfl_xor(t, 8, 64);
      l_run[r] = l_run[r] * fs[r] + t;
#pragma unroll
      for (int f = 0; f < 4; ++f) o[f][r] *= fs[r];
    }
    asm volatile("s_waitcnt lgkmcnt(0)" ::: "memory");
    __builtin_amdgcn_sched_barrier(0);
    bf16x8 pa0 = *(const bf16x8*)&Ps[w][c][8 * g];
    bf16x8 pa1 = *(const bf16x8*)&Ps[w][c][32 + 8 * g];
#pragma unroll
    for (int f = 0; f < 4; ++f) {
      bf16x8 vb0 = *(const bf16x8*)&Vt[16 * f + c][8 * g];
      bf16x8 vb1 = *(const bf16x8*)&Vt[16 * f + c][32 + 8 * g];
      o[f] = __builtin_amdgcn_mfma_f32_16x16x32_bf16(pa0, vb0, o[f], 0, 0, 0);
      o[f] = __builtin_amdgcn_mfma_f32_16x16x32_bf16(pa1, vb1, o[f], 0, 0, 0);
    }
  }
#pragma unroll
  for (int r = 0; r < 4; ++r) {
    int tok = b * NN + q0 + 16 * w + 4 * g + r;
    float invl = 1.f / l_run[r];
#pragma unroll
    for (int f = 0; f < 4; ++f) {
      float vv = o[f][r] * invl;
      size_t idx = (size_t)tok * DD + hh * DHH + 16 * f + c;
      unsigned short h = f2bf(vv);
      ohi[idx] = h; olo[idx] = f2bf(vv - bf2f(h));
    }
  }
}

// ---------- weight transpose + bf16 hi/lo split: W[z][K][N] -> Wt{hi,lo}[z][N][K] ----------
__global__ __launch_bounds__(256) void k_wsplit(const float* __restrict__ W,
    unsigned short* __restrict__ Whi, unsigned short* __restrict__ Wlo, int K, int N) {
  __shared__ float tile[64][65];
  size_t zoff = (size_t)blockIdx.z * K * N;
  W += zoff; Whi += zoff; Wlo += zoff;
  int k0 = blockIdx.y * 64, n0 = blockIdx.x * 64;
  int tid = threadIdx.x;
#pragma unroll
  for (int it = 0; it < 4; ++it) {
    int r = (tid >> 4) + it * 16;
    int c = (tid & 15) * 4;
    float4 v = *(const float4*)&W[(size_t)(k0 + r) * N + n0 + c];
    tile[r][c] = v.x; tile[r][c+1] = v.y; tile[r][c+2] = v.z; tile[r][c+3] = v.w;
  }
  __syncthreads();
  int n = tid >> 2;
  int kb = (tid & 3) * 16;
  bf16x8 h0, h1, l0, l1;
#pragma unroll
  for (int i = 0; i < 8; ++i) {
    float xv = tile[kb + i][n];
    unsigned short h = f2bf(xv);
    h0[i] = (short)h; l0[i] = (short)f2bf(xv - bf2f(h));
  }
#pragma unroll
  for (int i = 0; i < 8; ++i) {
    float xv = tile[kb + 8 + i][n];
    unsigned short h = f2bf(xv);
    h1[i] = (short)h; l1[i] = (short)f2bf(xv - bf2f(h));
  }
  size_t ob = (size_t)(n0 + n) * K + k0 + kb;
  *(bf16x8*)&Whi[ob] = h0; *(bf16x8*)&Whi[ob + 8] = h1;
  *(bf16x8*)&Wlo[ob] = l0; *(bf16x8*)&Wlo[ob + 8] = l1;
}

// ---------- split-bf16 MFMA GEMM: C[T x Nc] = A @ W ----------
// SPLIT: 0 = fp32 out, 1 = split hi/lo out, 2 = plain bf16 out (Chi). NT: nontemporal fp32 store.
// grid.z = split-K chunks (deterministic): z=0 -> C, z=1 -> C1.
// Block remap: XCD-bijective swizzle + N-chunks of CHX panels, by-fastest (W-panel L2 reuse).
template<int ACT, int SPLIT, int NT>
__global__ __launch_bounds__(256) void k_mgemm(
    const unsigned short* __restrict__ Ahi, const unsigned short* __restrict__ Alo,
    const unsigned short* __restrict__ Whi, const unsigned short* __restrict__ Wlo,
    const float* __restrict__ bias, float* __restrict__ C, float* __restrict__ C1,
    unsigned short* __restrict__ Chi, unsigned short* __restrict__ Clo,
    int K, int Nc, int CHX) {
  __shared__ unsigned short AsH[128*32], AsL[128*32], BsH[128*32], BsL[128*32];
  int nbx = gridDim.x, nby = gridDim.y;
  int bid = blockIdx.y * nbx + blockIdx.x;
  int nwg = nbx * nby;                      // always % 8 == 0 here
  int sw = (bid & 7) * (nwg >> 3) + (bid >> 3);
  int per = CHX * nby;
  int st = sw / per, off = sw - st * per;
  int bx = st * CHX + off / nby;            // panel (slow)
  int by = off % nby;                       // M-row (fast) -> W panel stays in L2
  int brow = by * 128, bcol = bx * 128;
  int Kc = K / gridDim.z;
  int kbeg = blockIdx.z * Kc;
  float* Cz = (blockIdx.z == 0) ? C : C1;
  int tid = threadIdx.x;
  int w = tid >> 6, l = tid & 63;
  int wr = w >> 1, wc = w & 1;
  int lr = l & 15;
  int lk = l >> 4;
  int srow = w * 16 + (l >> 2);
  int skc = (l & 3) * 8;
  const unsigned short* pAh = Ahi + (size_t)(brow + srow) * K + kbeg + skc;
  const unsigned short* pAl = Alo + (size_t)(brow + srow) * K + kbeg + skc;
  const unsigned short* pBh = Whi + (size_t)(bcol + srow) * K + kbeg + skc;
  const unsigned short* pBl = Wlo + (size_t)(bcol + srow) * K + kbeg + skc;
  size_t half = (size_t)64 * K;
  f32x4 acc[4][4];
#pragma unroll
  for (int i = 0; i < 4; ++i)
#pragma unroll
    for (int j = 0; j < 4; ++j) acc[i][j] = (f32x4){0.f, 0.f, 0.f, 0.f};
  int sAo = srow * 32 + skc;
  for (int k0 = 0; k0 < Kc; k0 += 32) {
    __syncthreads();
    gl16(pAh, &AsH[sAo]); gl16(pAh + half, &AsH[sAo + 64*32]);
    gl16(pAl, &AsL[sAo]); gl16(pAl + half, &AsL[sAo + 64*32]);
    gl16(pBh, &BsH[sAo]); gl16(pBh + half, &BsH[sAo + 64*32]);
    gl16(pBl, &BsL[sAo]); gl16(pBl + half, &BsL[sAo + 64*32]);
    pAh += 32; pAl += 32; pBh += 32; pBl += 32;
    __syncthreads();
    bf16x8 ah[4], al[4], bh[4], bl[4];
#pragma unroll
    for (int i = 0; i < 4; ++i) {
      int ar = (wr*64 + i*16 + lr) * 32 + lk*8;
      int br = (wc*64 + i*16 + lr) * 32 + lk*8;
      ah[i] = *(const bf16x8*)&AsH[ar];
      al[i] = *(const bf16x8*)&AsL[ar];
      bh[i] = *(const bf16x8*)&BsH[br];
      bl[i] = *(const bf16x8*)&BsL[br];
    }
#pragma unroll
    for (int mi = 0; mi < 4; ++mi)
#pragma unroll
      for (int ni = 0; ni < 4; ++ni) {
        acc[mi][ni] = __builtin_amdgcn_mfma_f32_16x16x32_bf16(ah[mi], bh[ni], acc[mi][ni], 0, 0, 0);
        acc[mi][ni] = __builtin_amdgcn_mfma_f32_16x16x32_bf16(ah[mi], bl[ni], acc[mi][ni], 0, 0, 0);
        acc[mi][ni] = __builtin_amdgcn_mfma_f32_16x16x32_bf16(al[mi], bh[ni], acc[mi][ni], 0, 0, 0);
      }
  }
#pragma unroll
  for (int mi = 0; mi < 4; ++mi) {
    int row0 = brow + wr*64 + mi*16 + lk*4;
#pragma unroll
    for (int ni = 0; ni < 4; ++ni) {
      int col = bcol + wc*64 + ni*16 + lr;
      float bv = bias ? bias[col] : 0.f;
#pragma unroll
      for (int r = 0; r < 4; ++r) {
        float v = acc[mi][ni][r] + bv;
        if (ACT == 1) v = 0.5f * v * (1.f + erff(v * 0.70710678118654752f));
        size_t idx = (size_t)(row0 + r) * Nc + col;
        if (SPLIT == 1) {
          unsigned short h = f2bf(v);
          Chi[idx] = h; Clo[idx] = f2bf(v - bf2f(h));
        } else if (SPLIT == 2) {
          Chi[idx] = f2bf(v);
        } else {
          if (NT) __builtin_nontemporal_store(v, &Cz[idx]);
          else Cz[idx] = v;
        }
      }
    }
  }
}

// ---------- copy h[:,0,:] to second output ----------
__global__ void k_copyh0(const float* __restrict__ h, float* __restrict__ o2) {
  int i = blockIdx.x * 256 + threadIdx.x;
  if (i < BB * DD) {
    int b = i / DD, d = i - b * DD;
    o2[i] = h[(size_t)(b * NN) * DD + d];
  }
}

extern "C" void kernel_launch(void* const* d_in, const int* in_sizes, int n_in,
                              void* d_out, int out_size, void* d_ws, size_t ws_size,
                              hipStream_t stream) {
  const float* tok_emb = (const float*)d_in[0];
  const float* emb_g  = (const float*)d_in[1];
  const float* emb_b  = (const float*)d_in[2];
  const float* n1_g   = (const float*)d_in[3];
  const float* n1_b   = (const float*)d_in[4];
  const float* n2_g   = (const float*)d_in[5];
  const float* n2_b   = (const float*)d_in[6];
  const float* qkv_w  = (const float*)d_in[7];
  const float* out_w  = (const float*)d_in[8];
  const float* ff_g   = (const float*)d_in[9];
  const float* ff_b   = (const float*)d_in[10];
  const float* ff_w1  = (const float*)d_in[11];
  const float* ff_b1  = (const float*)d_in[12];
  const float* ff_w2  = (const float*)d_in[13];
  const float* ff_b2  = (const float*)d_in[14];
  const float* h_w1   = (const float*)d_in[15];
  const float* h_b1   = (const float*)d_in[16];
  const float* h_g    = (const float*)d_in[17];
  const float* h_b    = (const float*)d_in[18];
  const float* h_w2   = (const float*)d_in[19];
  const float* h_b2   = (const float*)d_in[20];
  const int*   xi     = (const int*)d_in[21];
  float* outp = (float*)d_out;

  size_t szH  = (size_t)TT * DD;          // floats
  size_t szAM = (size_t)TT * MFF;         // ushorts per split act buffer
  size_t szQ  = (size_t)TT * 3 * DD;      // ushorts (qkv bf16)
  size_t szW  = (size_t)DD * VV;          // ushorts per shared split weight buffer
  size_t szRT = (size_t)NN * 16;          // floats per rope table

  size_t eQKV = (size_t)NLAYER * DD * 3 * DD;
  size_t eOUT = (size_t)NLAYER * DD * DD;
  size_t eFF1 = (size_t)NLAYER * DD * MFF;
  size_t eFF2 = (size_t)NLAYER * MFF * DD;
  size_t eHW1 = (size_t)DD * DD;
  size_t eLG  = (size_t)DD * VV;
  size_t eWT  = eQKV + eOUT + eFF1 + eFF2 + eHW1 + eLG;

  size_t actBytes = szH*4*3 + szQ*2 + szAM*2*4 + szRT*4*2;
  size_t needFull = actBytes + eWT * 2 * 2;

  char* p = (char*)d_ws;
  float* h   = (float*)p;                   p += szH * 4;
  float* t1  = (float*)p;                   p += szH * 4;
  float* t3  = (float*)p;                   p += szH * 4;
  unsigned short* t1b = (unsigned short*)p; p += szQ * 2;
  unsigned short* ahi = (unsigned short*)p; p += szAM * 2;
  unsigned short* alo = (unsigned short*)p; p += szAM * 2;
  unsigned short* bhi = (unsigned short*)p; p += szAM * 2;
  unsigned short* blo = (unsigned short*)p; p += szAM * 2;
  float* ropc = (float*)p;                  p += szRT * 4;
  float* rops = (float*)p;                  p += szRT * 4;

  bool full = (ws_size >= needFull);
  unsigned short *qkvh, *qkvl, *outh, *outl, *f1h, *f1l, *f2h, *f2l, *hw1h, *hw1l, *lgh, *lgl;
  unsigned short *whi = nullptr, *wlo = nullptr;
  if (full) {
    qkvh = (unsigned short*)p; p += eQKV * 2; qkvl = (unsigned short*)p; p += eQKV * 2;
    outh = (unsigned short*)p; p += eOUT * 2; outl = (unsigned short*)p; p += eOUT * 2;
    f1h  = (unsigned short*)p; p += eFF1 * 2; f1l  = (unsigned short*)p; p += eFF1 * 2;
    f2h  = (unsigned short*)p; p += eFF2 * 2; f2l  = (unsigned short*)p; p += eFF2 * 2;
    hw1h = (unsigned short*)p; p += eHW1 * 2; hw1l = (unsigned short*)p; p += eHW1 * 2;
    lgh  = (unsigned short*)p; p += eLG * 2;  lgl  = (unsigned short*)p;
    k_wsplit<<<dim3(3*DD/64, DD/64, NLAYER), 256, 0, stream>>>(qkv_w, qkvh, qkvl, DD, 3*DD);
    k_wsplit<<<dim3(DD/64, DD/64, NLAYER), 256, 0, stream>>>(out_w, outh, outl, DD, DD);
    k_wsplit<<<dim3(MFF/64, DD/64, NLAYER), 256, 0, stream>>>(ff_w1, f1h, f1l, DD, MFF);
    k_wsplit<<<dim3(DD/64, MFF/64, NLAYER), 256, 0, stream>>>(ff_w2, f2h, f2l, MFF, DD);
    k_wsplit<<<dim3(DD/64, DD/64, 1), 256, 0, stream>>>(h_w1, hw1h, hw1l, DD, DD);
    k_wsplit<<<dim3(VV/64, DD/64, 1), 256, 0, stream>>>(h_w2, lgh, lgl, DD, VV);
  } else {
    whi = (unsigned short*)p; p += szW * 2;
    wlo = (unsigned short*)p;
  }

  k_ropetab<<<(NN*16 + 255)/256, 256, 0, stream>>>(ropc, rops);
  k_embed_ln<<<TT, 256, 0, stream>>>(tok_emb, emb_g, emb_b, xi, h, ahi, alo);
  for (int l = 0; l < NLAYER; ++l) {
    const unsigned short *wh, *wl;
    // ---- qkv ----
    if (full) { wh = qkvh + (size_t)l * DD * 3 * DD; wl = qkvl + (size_t)l * DD * 3 * DD; }
    else {
      k_wsplit<<<dim3(3*DD/64, DD/64, 1), 256, 0, stream>>>(
          qkv_w + (size_t)l * DD * 3 * DD, whi, wlo, DD, 3*DD);
      wh = whi; wl = wlo;
    }
    k_mgemm<0,2,0><<<dim3(3*DD/128, TT/128, 1), 256, 0, stream>>>(
        ahi, alo, wh, wl, nullptr, nullptr, nullptr, t1b, nullptr, DD, 3*DD, 6);
    k_attn<<<BB * HH * (NN/64), 256, 0, stream>>>(t1b, xi, ropc, rops, ahi, alo);
    // ---- attn out (split-K=2 -> t1,t3; reduce+2xLN fused) ----
    if (full) { wh = outh + (size_t)l * DD * DD; wl = outl + (size_t)l * DD * DD; }
    else {
      k_wsplit<<<dim3(DD/64, DD/64, 1), 256, 0, stream>>>(
          out_w + (size_t)l * DD * DD, whi, wlo, DD, DD);
      wh = whi; wl = wlo;
    }
    k_mgemm<0,0,0><<<dim3(DD/128, TT/128, 2), 256, 0, stream>>>(
        ahi, alo, wh, wl, nullptr, t1, t3, nullptr, nullptr, DD, DD, 6);
    k_lnS<2,0,1><<<TT, 256, 0, stream>>>(t1, t3, nullptr, h, n1_g, n1_b,
        ff_g + (size_t)l*DD, ff_b + (size_t)l*DD, h, ahi, alo);
    // ---- ff1 ----
    if (full) { wh = f1h + (size_t)l * DD * MFF; wl = f1l + (size_t)l * DD * MFF; }
    else {
      k_wsplit<<<dim3(MFF/64, DD/64, 1), 256, 0, stream>>>(
          ff_w1 + (size_t)l * DD * MFF, whi, wlo, DD, MFF);
      wh = whi; wl = wlo;
    }
    k_mgemm<1,1,0><<<dim3(MFF/128, TT/128, 1), 256, 0, stream>>>(
        ahi, alo, wh, wl, ff_b1 + (size_t)l*MFF, nullptr, nullptr, bhi, blo, DD, MFF, 8);
    // ---- ff2 (split-K=2 -> t1,t3; reduce+bias+LN fused) ----
    if (full) { wh = f2h + (size_t)l * MFF * DD; wl = f2l + (size_t)l * MFF * DD; }
    else {
      k_wsplit<<<dim3(DD/64, MFF/64, 1), 256, 0, stream>>>(
          ff_w2 + (size_t)l * MFF * DD, whi, wlo, MFF, DD);
      wh = whi; wl = wlo;
    }
    k_mgemm<0,0,0><<<dim3(DD/128, TT/128, 2), 256, 0, stream>>>(
        bhi, blo, wh, wl, nullptr, t1, t3, nullptr, nullptr, MFF, DD, 6);
    k_lnS<2,0,0><<<TT, 256, 0, stream>>>(t1, t3, ff_b2 + (size_t)l*DD, h,
        n2_g, n2_b, nullptr, nullptr, h, ahi, alo);
  }
  // ---- head: w1 (split-K=2), then bias+GELU+LN fused reducer ----
  {
    const unsigned short *wh, *wl;
    if (full) { wh = hw1h; wl = hw1l; }
    else {
      k_wsplit<<<dim3(DD/64, DD/64, 1), 256, 0, stream>>>(h_w1, whi, wlo, DD, DD);
      wh = whi; wl = wlo;
    }
    k_mgemm<0,0,0><<<dim3(DD/128, TT/128, 2), 256, 0, stream>>>(
        ahi, alo, wh, wl, nullptr, t1, t3, nullptr, nullptr, DD, DD, 6);
    k_lnS<2,1,0><<<TT, 256, 0, stream>>>(t1, t3, h_b1, nullptr, h_g, h_b,
        nullptr, nullptr, nullptr, ahi, alo);
    if (full) { wh = lgh; wl = lgl; }
    else {
      k_wsplit<<<dim3(VV/64, DD/64, 1), 256, 0, stream>>>(h_w2, whi, wlo, DD, VV);
      wh = whi; wl = wlo;
    }
    k_mgemm<0,0,1><<<dim3(VV/128, TT/128, 1), 256, 0, stream>>>(
        ahi, alo, wh, wl, h_b2, outp, nullptr, nullptr, nullptr, DD, VV, 10);
  }
  k_copyh0<<<(BB * DD + 255) / 256, 256, 0, stream>>>(h, outp + (size_t)TT * VV);
}

// Round 6
// 3812.631 us; speedup vs baseline: 4.0047x; 1.3476x over previous
//
#include <hip/hip_runtime.h>
#include <math.h>

#define DD 768
#define HH 12
#define DHH 64
#define NLAYER 12
#define MFF 3072
#define VV 32000
#define BB 8
#define NN 512
#define TT (BB*NN)

typedef __attribute__((ext_vector_type(8))) short bf16x8;
typedef __attribute__((ext_vector_type(4))) float f32x4;

// ---------- bf16 split helpers (RTNE) ----------
__device__ __forceinline__ unsigned short f2bf(float x) {
  unsigned u = __float_as_uint(x);
  unsigned r = u + 0x7FFFu + ((u >> 16) & 1u);
  return (unsigned short)(r >> 16);
}
__device__ __forceinline__ float bf2f(unsigned short h) {
  return __uint_as_float(((unsigned)h) << 16);
}

// ---------- async global->LDS 16B ----------
__device__ __forceinline__ void gl16(const void* g, void* l) {
  __builtin_amdgcn_global_load_lds(
      (const __attribute__((address_space(1))) unsigned*)g,
      (__attribute__((address_space(3))) unsigned*)l, 16, 0, 0);
}

// ---------- block-wide sum reduction of two values (256 threads = 4 waves) ----------
__device__ __forceinline__ void blockReduce2(float& a, float& b, float* sh) {
#pragma unroll
  for (int off = 32; off > 0; off >>= 1) {
    a += __shfl_down(a, off, 64);
    b += __shfl_down(b, off, 64);
  }
  int lane = threadIdx.x & 63;
  int w = threadIdx.x >> 6;
  if (lane == 0) { sh[2*w] = a; sh[2*w+1] = b; }
  __syncthreads();
  a = sh[0] + sh[2] + sh[4] + sh[6];
  b = sh[1] + sh[3] + sh[5] + sh[7];
}

// ---------- rope cos/sin tables: [NN][16] ----------
__global__ void k_ropetab(float* __restrict__ rc, float* __restrict__ rsn) {
  int i = blockIdx.x * 256 + threadIdx.x;
  if (i < NN * 16) {
    int pos = i >> 4, pr = i & 15;
    float inv = expf(-0.57564627324851148f * (float)pr);  // 10000^(-pr/16)
    float ang = (float)pos * inv;
    rc[i] = cosf(ang); rsn[i] = sinf(ang);
  }
}

// ---------- embedding gather + sinusoid PE + LayerNorm (+ bf16 split out) ----------
__global__ __launch_bounds__(256) void k_embed_ln(const float* __restrict__ emb,
    const float* __restrict__ g, const float* __restrict__ bb,
    const int* __restrict__ x, float* __restrict__ out,
    unsigned short* __restrict__ ohi, unsigned short* __restrict__ olo) {
  __shared__ float sh[8];
  int tok = blockIdx.x;
  int n = tok & (NN - 1);
  int t = x[tok];
  const float* row = emb + (size_t)t * DD;
  float v[3]; float s = 0.f, ss = 0.f;
#pragma unroll
  for (int i = 0; i < 3; ++i) {
    int d = threadIdx.x + 256 * i;
    int pair = d >> 1;
    float div = expf((float)(2 * pair) * (-9.210340371976184f / (float)DD));
    float ang = (float)n * div;
    float pe = (d & 1) ? cosf(ang) : sinf(ang);
    float val = row[d] + pe;
    v[i] = val; s += val; ss += val * val;
  }
  blockReduce2(s, ss, sh);
  float mu = s * (1.f / DD);
  float var = ss * (1.f / DD) - mu * mu;
  float rs = rsqrtf(var + 1e-5f);
#pragma unroll
  for (int i = 0; i < 3; ++i) {
    int d = threadIdx.x + 256 * i;
    float val = (v[i] - mu) * rs * g[d] + bb[d];
    size_t idx = (size_t)tok * DD + d;
    out[idx] = val;
    unsigned short h = f2bf(val); ohi[idx] = h; olo[idx] = f2bf(val - bf2f(h));
  }
}

// ---------- fused reducer + LayerNorm(s) ----------
template<int NP, int GELU, int LN2>
__global__ __launch_bounds__(256) void k_lnS(
    const float* __restrict__ p0, const float* __restrict__ p1,
    const float* __restrict__ bias, const float* __restrict__ res,
    const float* __restrict__ g1, const float* __restrict__ b1v,
    const float* __restrict__ g2, const float* __restrict__ b2v,
    float* __restrict__ outf,
    unsigned short* __restrict__ ohi, unsigned short* __restrict__ olo) {
  __shared__ float sh[8];
  int tok = blockIdx.x;
  float v[3]; float s = 0.f, ss = 0.f;
#pragma unroll
  for (int i = 0; i < 3; ++i) {
    int d = threadIdx.x + 256 * i;
    size_t idx = (size_t)tok * DD + d;
    float val = p0[idx];
    if (NP > 1) val += p1[idx];
    if (bias) val += bias[d];
    if (res) val += res[idx];
    if (GELU) val = 0.5f * val * (1.f + erff(val * 0.70710678118654752f));
    v[i] = val; s += val; ss += val * val;
  }
  blockReduce2(s, ss, sh);
  float mu = s * (1.f / DD);
  float var = ss * (1.f / DD) - mu * mu;
  float rs = rsqrtf(var + 1e-5f);
  if (LN2) {
    float y[3]; float s2 = 0.f, ss2 = 0.f;
#pragma unroll
    for (int i = 0; i < 3; ++i) {
      int d = threadIdx.x + 256 * i;
      float yy = (v[i] - mu) * rs * g1[d] + b1v[d];
      y[i] = yy; s2 += yy; ss2 += yy * yy;
      outf[(size_t)tok * DD + d] = yy;
    }
    __syncthreads();
    blockReduce2(s2, ss2, sh);
    float mu2 = s2 * (1.f / DD);
    float var2 = ss2 * (1.f / DD) - mu2 * mu2;
    float rs2 = rsqrtf(var2 + 1e-5f);
#pragma unroll
    for (int i = 0; i < 3; ++i) {
      int d = threadIdx.x + 256 * i;
      float val = (y[i] - mu2) * rs2 * g2[d] + b2v[d];
      size_t idx = (size_t)tok * DD + d;
      unsigned short h = f2bf(val); ohi[idx] = h; olo[idx] = f2bf(val - bf2f(h));
    }
  } else {
#pragma unroll
    for (int i = 0; i < 3; ++i) {
      int d = threadIdx.x + 256 * i;
      float val = (v[i] - mu) * rs * g1[d] + b1v[d];
      size_t idx = (size_t)tok * DD + d;
      if (outf) outf[idx] = val;
      unsigned short h = f2bf(val); ohi[idx] = h; olo[idx] = f2bf(val - bf2f(h));
    }
  }
}

// ---------- RoPE on 8 packed bf16 (4 pairs) via table, base = pos*16 + pair0 ----------
__device__ __forceinline__ void rope8t(bf16x8& v, const float* __restrict__ rc,
    const float* __restrict__ rsn, int base) {
#pragma unroll
  for (int i = 0; i < 4; ++i) {
    float cs = rc[base + i];
    float sn = rsn[base + i];
    float x0 = bf2f((unsigned short)v[2*i]);
    float x1 = bf2f((unsigned short)v[2*i+1]);
    v[2*i]   = (short)f2bf(x0 * cs - x1 * sn);
    v[2*i+1] = (short)f2bf(x1 * cs + x0 * sn);
  }
}

// ---------- MFMA flash attention: block = 64 q rows of one (b,h), 4 waves x 16 rows ----------
__global__ __launch_bounds__(256) void k_attn(const unsigned short* __restrict__ qkvb,
    const int* __restrict__ x, const float* __restrict__ rc, const float* __restrict__ rsn,
    unsigned short* __restrict__ ohi, unsigned short* __restrict__ olo) {
  __shared__ unsigned short Ks[64][72];
  __shared__ unsigned short Vt[64][72];
  __shared__ unsigned short Ps[4][16][72];
  __shared__ float maskv[64];
  int nblk = gridDim.x;
  int bid = blockIdx.x;
  int blk = (bid & 7) * (nblk >> 3) + (bid >> 3);
  int qb = blk & 7;
  int hh = (blk >> 3) % HH;
  int b = blk / (8 * HH);
  int q0 = qb * 64;
  int tid = threadIdx.x;
  int w = tid >> 6, l = tid & 63;
  int g = l >> 4, c = l & 15;

  bf16x8 qa0, qa1;
  {
    int q = q0 + 16 * w + c;
    const unsigned short* qp = qkvb + (size_t)(b * NN + q) * (3 * DD) + hh * DHH;
    qa0 = *(const bf16x8*)(qp + 8 * g);
    qa1 = *(const bf16x8*)(qp + 32 + 8 * g);
    rope8t(qa0, rc, rsn, q * 16 + 4 * g);
  }
  f32x4 o[4];
#pragma unroll
  for (int f = 0; f < 4; ++f) o[f] = (f32x4){0.f,0.f,0.f,0.f};
  float m_run[4] = {-INFINITY,-INFINITY,-INFINITY,-INFINITY};
  float l_run[4] = {0.f,0.f,0.f,0.f};

  int kr = tid >> 2;
  int kd = (tid & 3) * 16;
  for (int kt = 0; kt < NN; kt += 64) {
    __syncthreads();
    {
      int tok = b * NN + kt + kr;
      const unsigned short* kp = qkvb + (size_t)tok * (3 * DD) + DD + hh * DHH + kd;
      const unsigned short* vp = kp + DD;
      bf16x8 k0 = *(const bf16x8*)kp;
      bf16x8 k1 = *(const bf16x8*)(kp + 8);
      if (kd < 32) {
        int base = (kt + kr) * 16 + kd / 2;
        rope8t(k0, rc, rsn, base);
        rope8t(k1, rc, rsn, base + 4);
      }
      *(bf16x8*)&Ks[kr][kd] = k0;
      *(bf16x8*)&Ks[kr][kd + 8] = k1;
      bf16x8 v0 = *(const bf16x8*)vp;
      bf16x8 v1 = *(const bf16x8*)(vp + 8);
#pragma unroll
      for (int j = 0; j < 8; ++j) {
        Vt[kd + j][kr] = (unsigned short)v0[j];
        Vt[kd + 8 + j][kr] = (unsigned short)v1[j];
      }
    }
    if (tid < 64) maskv[tid] = (x[b * NN + kt + tid] == 0) ? 1.f : 0.f;
    __syncthreads();

    f32x4 sc[4];
#pragma unroll
    for (int f = 0; f < 4; ++f) {
      bf16x8 kb0 = *(const bf16x8*)&Ks[16 * f + c][8 * g];
      bf16x8 kb1 = *(const bf16x8*)&Ks[16 * f + c][32 + 8 * g];
      f32x4 sacc = (f32x4){0.f,0.f,0.f,0.f};
      sacc = __builtin_amdgcn_mfma_f32_16x16x32_bf16(qa0, kb0, sacc, 0, 0, 0);
      sacc = __builtin_amdgcn_mfma_f32_16x16x32_bf16(qa1, kb1, sacc, 0, 0, 0);
      float mk = maskv[16 * f + c];
#pragma unroll
      for (int r = 0; r < 4; ++r) {
        float sv = sacc[r] * 0.125f;
        sacc[r] = (mk != 0.f) ? 1e-9f : sv;
      }
      sc[f] = sacc;
    }
    float fs[4];
#pragma unroll
    for (int r = 0; r < 4; ++r) {
      float m = fmaxf(fmaxf(sc[0][r], sc[1][r]), fmaxf(sc[2][r], sc[3][r]));
      m = fmaxf(m, __shfl_xor(m, 1, 64));
      m = fmaxf(m, __shfl_xor(m, 2, 64));
      m = fmaxf(m, __shfl_xor(m, 4, 64));
      m = fmaxf(m, __shfl_xor(m, 8, 64));
      float mn = fmaxf(m_run[r], m);
      fs[r] = expf(m_run[r] - mn);
      m_run[r] = mn;
    }
    float tsum[4] = {0.f,0.f,0.f,0.f};
#pragma unroll
    for (int f = 0; f < 4; ++f)
#pragma unroll
      for (int r = 0; r < 4; ++r) {
        float p = expf(sc[f][r] - m_run[r]);
        Ps[w][4 * g + r][16 * f + c] = f2bf(p);
        tsum[r] += p;
      }
#pragma unroll
    for (int r = 0; r < 4; ++r) {
      float t = tsum[r];
      t += __shfl_xor(t, 1, 64);
      t += __shfl_xor(t, 2, 64);
      t += __shfl_xor(t, 4, 64);
      t += __shfl_xor(t, 8, 64);
      l_run[r] = l_run[r] * fs[r] + t;
#pragma unroll
      for (int f = 0; f < 4; ++f) o[f][r] *= fs[r];
    }
    asm volatile("s_waitcnt lgkmcnt(0)" ::: "memory");
    __builtin_amdgcn_sched_barrier(0);
    bf16x8 pa0 = *(const bf16x8*)&Ps[w][c][8 * g];
    bf16x8 pa1 = *(const bf16x8*)&Ps[w][c][32 + 8 * g];
#pragma unroll
    for (int f = 0; f < 4; ++f) {
      bf16x8 vb0 = *(const bf16x8*)&Vt[16 * f + c][8 * g];
      bf16x8 vb1 = *(const bf16x8*)&Vt[16 * f + c][32 + 8 * g];
      o[f] = __builtin_amdgcn_mfma_f32_16x16x32_bf16(pa0, vb0, o[f], 0, 0, 0);
      o[f] = __builtin_amdgcn_mfma_f32_16x16x32_bf16(pa1, vb1, o[f], 0, 0, 0);
    }
  }
#pragma unroll
  for (int r = 0; r < 4; ++r) {
    int tok = b * NN + q0 + 16 * w + 4 * g + r;
    float invl = 1.f / l_run[r];
#pragma unroll
    for (int f = 0; f < 4; ++f) {
      float vv = o[f][r] * invl;
      size_t idx = (size_t)tok * DD + hh * DHH + 16 * f + c;
      unsigned short h = f2bf(vv);
      ohi[idx] = h; olo[idx] = f2bf(vv - bf2f(h));
    }
  }
}

// ---------- weight transpose + bf16 hi/lo split: W[z][K][N] -> Wt{hi[,lo]}[z][N][K] ----------
template<int WLO>
__global__ __launch_bounds__(256) void k_wsplit(const float* __restrict__ W,
    unsigned short* __restrict__ Whi, unsigned short* __restrict__ Wlo, int K, int N) {
  __shared__ float tile[64][65];
  size_t zoff = (size_t)blockIdx.z * K * N;
  W += zoff; Whi += zoff; if (WLO) Wlo += zoff;
  int k0 = blockIdx.y * 64, n0 = blockIdx.x * 64;
  int tid = threadIdx.x;
#pragma unroll
  for (int it = 0; it < 4; ++it) {
    int r = (tid >> 4) + it * 16;
    int c = (tid & 15) * 4;
    float4 v = *(const float4*)&W[(size_t)(k0 + r) * N + n0 + c];
    tile[r][c] = v.x; tile[r][c+1] = v.y; tile[r][c+2] = v.z; tile[r][c+3] = v.w;
  }
  __syncthreads();
  int n = tid >> 2;
  int kb = (tid & 3) * 16;
  bf16x8 h0, h1, l0, l1;
#pragma unroll
  for (int i = 0; i < 8; ++i) {
    float xv = tile[kb + i][n];
    unsigned short h = f2bf(xv);
    h0[i] = (short)h; l0[i] = (short)f2bf(xv - bf2f(h));
  }
#pragma unroll
  for (int i = 0; i < 8; ++i) {
    float xv = tile[kb + 8 + i][n];
    unsigned short h = f2bf(xv);
    h1[i] = (short)h; l1[i] = (short)f2bf(xv - bf2f(h));
  }
  size_t ob = (size_t)(n0 + n) * K + k0 + kb;
  *(bf16x8*)&Whi[ob] = h0; *(bf16x8*)&Whi[ob + 8] = h1;
  if (WLO) { *(bf16x8*)&Wlo[ob] = l0; *(bf16x8*)&Wlo[ob + 8] = l1; }
}

// ---------- split-bf16 MFMA GEMM: C[T x Nc] = A @ W ----------
// TERMS: 3 = Ahi*Whi + Ahi*Wlo + Alo*Whi ; 2 = (Ahi+Alo)*Whi (Wlo never read)
// SPLIT: 0 = fp32 out (Cz), 1 = split hi/lo out, 2 = plain bf16 out (Chi). NT: nontemporal.
// grid.z = deterministic split-K chunks: z=0 -> C, z=1 -> C1.
// Block remap: XCD-bijective swizzle + N-chunks of CHX panels (bx fast within chunk).
template<int ACT, int SPLIT, int NT, int TERMS>
__global__ __launch_bounds__(256) void k_mgemm(
    const unsigned short* __restrict__ Ahi, const unsigned short* __restrict__ Alo,
    const unsigned short* __restrict__ Whi, const unsigned short* __restrict__ Wlo,
    const float* __restrict__ bias, float* __restrict__ C, float* __restrict__ C1,
    unsigned short* __restrict__ Chi, unsigned short* __restrict__ Clo,
    int K, int Nc, int CHX) {
  __shared__ unsigned short AsH[128*32], AsL[128*32], BsH[128*32];
  __shared__ unsigned short BsL[(TERMS == 3) ? 128*32 : 8];
  int nbx = gridDim.x, nby = gridDim.y;
  int bid = blockIdx.y * nbx + blockIdx.x;
  int nwg = nbx * nby;
  int sw = (bid & 7) * (nwg >> 3) + (bid >> 3);
  int per = CHX * nby;
  int st = sw / per, off = sw - st * per;
  int bx = st * CHX + (off % CHX);
  int by = off / CHX;
  int brow = by * 128, bcol = bx * 128;
  int Kc = K / gridDim.z;
  int kbeg = blockIdx.z * Kc;
  float* Cz = (blockIdx.z == 0) ? C : C1;
  int tid = threadIdx.x;
  int w = tid >> 6, l = tid & 63;
  int wr = w >> 1, wc = w & 1;
  int lr = l & 15;
  int lk = l >> 4;
  int srow = w * 16 + (l >> 2);
  int skc = (l & 3) * 8;
  const unsigned short* pAh = Ahi + (size_t)(brow + srow) * K + kbeg + skc;
  const unsigned short* pAl = Alo + (size_t)(brow + srow) * K + kbeg + skc;
  const unsigned short* pBh = Whi + (size_t)(bcol + srow) * K + kbeg + skc;
  const unsigned short* pBl = (TERMS == 3) ? Wlo + (size_t)(bcol + srow) * K + kbeg + skc : nullptr;
  size_t half = (size_t)64 * K;
  f32x4 acc[4][4];
#pragma unroll
  for (int i = 0; i < 4; ++i)
#pragma unroll
    for (int j = 0; j < 4; ++j) acc[i][j] = (f32x4){0.f, 0.f, 0.f, 0.f};
  int sAo = srow * 32 + skc;
  for (int k0 = 0; k0 < Kc; k0 += 32) {
    __syncthreads();
    gl16(pAh, &AsH[sAo]); gl16(pAh + half, &AsH[sAo + 64*32]);
    gl16(pAl, &AsL[sAo]); gl16(pAl + half, &AsL[sAo + 64*32]);
    gl16(pBh, &BsH[sAo]); gl16(pBh + half, &BsH[sAo + 64*32]);
    if (TERMS == 3) { gl16(pBl, &BsL[sAo]); gl16(pBl + half, &BsL[sAo + 64*32]); pBl += 32; }
    pAh += 32; pAl += 32; pBh += 32;
    __syncthreads();
    bf16x8 ah[4], al[4], bh[4], bl[4];
#pragma unroll
    for (int i = 0; i < 4; ++i) {
      int ar = (wr*64 + i*16 + lr) * 32 + lk*8;
      int br = (wc*64 + i*16 + lr) * 32 + lk*8;
      ah[i] = *(const bf16x8*)&AsH[ar];
      al[i] = *(const bf16x8*)&AsL[ar];
      bh[i] = *(const bf16x8*)&BsH[br];
      if (TERMS == 3) bl[i] = *(const bf16x8*)&BsL[br];
    }
#pragma unroll
    for (int mi = 0; mi < 4; ++mi)
#pragma unroll
      for (int ni = 0; ni < 4; ++ni) {
        acc[mi][ni] = __builtin_amdgcn_mfma_f32_16x16x32_bf16(ah[mi], bh[ni], acc[mi][ni], 0, 0, 0);
        if (TERMS == 3)
          acc[mi][ni] = __builtin_amdgcn_mfma_f32_16x16x32_bf16(ah[mi], bl[ni], acc[mi][ni], 0, 0, 0);
        acc[mi][ni] = __builtin_amdgcn_mfma_f32_16x16x32_bf16(al[mi], bh[ni], acc[mi][ni], 0, 0, 0);
      }
  }
#pragma unroll
  for (int mi = 0; mi < 4; ++mi) {
    int row0 = brow + wr*64 + mi*16 + lk*4;
#pragma unroll
    for (int ni = 0; ni < 4; ++ni) {
      int col = bcol + wc*64 + ni*16 + lr;
      float bv = bias ? bias[col] : 0.f;
#pragma unroll
      for (int r = 0; r < 4; ++r) {
        float v = acc[mi][ni][r] + bv;
        if (ACT == 1) v = 0.5f * v * (1.f + erff(v * 0.70710678118654752f));
        size_t idx = (size_t)(row0 + r) * Nc + col;
        if (SPLIT == 1) {
          unsigned short h = f2bf(v);
          Chi[idx] = h; Clo[idx] = f2bf(v - bf2f(h));
        } else if (SPLIT == 2) {
          Chi[idx] = f2bf(v);
        } else {
          if (NT) __builtin_nontemporal_store(v, &Cz[idx]);
          else Cz[idx] = v;
        }
      }
    }
  }
}

// ---------- copy h[:,0,:] to second output ----------
__global__ void k_copyh0(const float* __restrict__ h, float* __restrict__ o2) {
  int i = blockIdx.x * 256 + threadIdx.x;
  if (i < BB * DD) {
    int b = i / DD, d = i - b * DD;
    o2[i] = h[(size_t)(b * NN) * DD + d];
  }
}

extern "C" void kernel_launch(void* const* d_in, const int* in_sizes, int n_in,
                              void* d_out, int out_size, void* d_ws, size_t ws_size,
                              hipStream_t stream) {
  const float* tok_emb = (const float*)d_in[0];
  const float* emb_g  = (const float*)d_in[1];
  const float* emb_b  = (const float*)d_in[2];
  const float* n1_g   = (const float*)d_in[3];
  const float* n1_b   = (const float*)d_in[4];
  const float* n2_g   = (const float*)d_in[5];
  const float* n2_b   = (const float*)d_in[6];
  const float* qkv_w  = (const float*)d_in[7];
  const float* out_w  = (const float*)d_in[8];
  const float* ff_g   = (const float*)d_in[9];
  const float* ff_b   = (const float*)d_in[10];
  const float* ff_w1  = (const float*)d_in[11];
  const float* ff_b1  = (const float*)d_in[12];
  const float* ff_w2  = (const float*)d_in[13];
  const float* ff_b2  = (const float*)d_in[14];
  const float* h_w1   = (const float*)d_in[15];
  const float* h_b1   = (const float*)d_in[16];
  const float* h_g    = (const float*)d_in[17];
  const float* h_b    = (const float*)d_in[18];
  const float* h_w2   = (const float*)d_in[19];
  const float* h_b2   = (const float*)d_in[20];
  const int*   xi     = (const int*)d_in[21];
  float* outp = (float*)d_out;

  size_t szH  = (size_t)TT * DD;          // floats
  size_t szAM = (size_t)TT * MFF;         // ushorts per split act buffer
  size_t szQ  = (size_t)TT * 3 * DD;      // ushorts (qkv bf16)
  size_t szW  = (size_t)DD * VV;          // ushorts per shared split weight buffer
  size_t szRT = (size_t)NN * 16;          // floats per rope table

  size_t eQKV = (size_t)NLAYER * DD * 3 * DD;
  size_t eOUT = (size_t)NLAYER * DD * DD;
  size_t eFF1 = (size_t)NLAYER * DD * MFF;
  size_t eFF2 = (size_t)NLAYER * MFF * DD;
  size_t eHW1 = (size_t)DD * DD;
  size_t eLG  = (size_t)DD * VV;
  // hi for all layer weights; hi+lo for head/logits
  size_t eWT_hi = eQKV + eOUT + eFF1 + eFF2;
  size_t eWT_hl = eHW1 + eLG;

  size_t actBytes = szH*4*3 + szQ*2 + szAM*2*4 + szRT*4*2;
  size_t needFull = actBytes + (eWT_hi + eWT_hl * 2) * 2;

  char* p = (char*)d_ws;
  float* h   = (float*)p;                   p += szH * 4;
  float* t1  = (float*)p;                   p += szH * 4;
  float* t3  = (float*)p;                   p += szH * 4;
  unsigned short* t1b = (unsigned short*)p; p += szQ * 2;
  unsigned short* ahi = (unsigned short*)p; p += szAM * 2;
  unsigned short* alo = (unsigned short*)p; p += szAM * 2;
  unsigned short* bhi = (unsigned short*)p; p += szAM * 2;
  unsigned short* blo = (unsigned short*)p; p += szAM * 2;
  float* ropc = (float*)p;                  p += szRT * 4;
  float* rops = (float*)p;                  p += szRT * 4;

  bool full = (ws_size >= needFull);
  unsigned short *qkvh, *outh, *f1h, *f2h, *hw1h, *hw1l, *lgh, *lgl;
  unsigned short *whi = nullptr, *wlo = nullptr;
  if (full) {
    qkvh = (unsigned short*)p; p += eQKV * 2;
    outh = (unsigned short*)p; p += eOUT * 2;
    f1h  = (unsigned short*)p; p += eFF1 * 2;
    f2h  = (unsigned short*)p; p += eFF2 * 2;
    hw1h = (unsigned short*)p; p += eHW1 * 2; hw1l = (unsigned short*)p; p += eHW1 * 2;
    lgh  = (unsigned short*)p; p += eLG * 2;  lgl  = (unsigned short*)p;
    k_wsplit<0><<<dim3(3*DD/64, DD/64, NLAYER), 256, 0, stream>>>(qkv_w, qkvh, nullptr, DD, 3*DD);
    k_wsplit<0><<<dim3(DD/64, DD/64, NLAYER), 256, 0, stream>>>(out_w, outh, nullptr, DD, DD);
    k_wsplit<0><<<dim3(MFF/64, DD/64, NLAYER), 256, 0, stream>>>(ff_w1, f1h, nullptr, DD, MFF);
    k_wsplit<0><<<dim3(DD/64, MFF/64, NLAYER), 256, 0, stream>>>(ff_w2, f2h, nullptr, MFF, DD);
    k_wsplit<1><<<dim3(DD/64, DD/64, 1), 256, 0, stream>>>(h_w1, hw1h, hw1l, DD, DD);
    k_wsplit<1><<<dim3(VV/64, DD/64, 1), 256, 0, stream>>>(h_w2, lgh, lgl, DD, VV);
  } else {
    whi = (unsigned short*)p; p += szW * 2;
    wlo = (unsigned short*)p;
  }

  k_ropetab<<<(NN*16 + 255)/256, 256, 0, stream>>>(ropc, rops);
  k_embed_ln<<<TT, 256, 0, stream>>>(tok_emb, emb_g, emb_b, xi, h, ahi, alo);
  for (int l = 0; l < NLAYER; ++l) {
    const unsigned short *wh;
    // ---- qkv (2-term) ----
    if (full) wh = qkvh + (size_t)l * DD * 3 * DD;
    else {
      k_wsplit<0><<<dim3(3*DD/64, DD/64, 1), 256, 0, stream>>>(
          qkv_w + (size_t)l * DD * 3 * DD, whi, nullptr, DD, 3*DD);
      wh = whi;
    }
    k_mgemm<0,2,0,2><<<dim3(3*DD/128, TT/128, 1), 256, 0, stream>>>(
        ahi, alo, wh, nullptr, nullptr, nullptr, nullptr, t1b, nullptr, DD, 3*DD, 6);
    k_attn<<<BB * HH * (NN/64), 256, 0, stream>>>(t1b, xi, ropc, rops, ahi, alo);
    // ---- attn out (2-term, split-K=2 -> t1,t3; reduce+2xLN fused) ----
    if (full) wh = outh + (size_t)l * DD * DD;
    else {
      k_wsplit<0><<<dim3(DD/64, DD/64, 1), 256, 0, stream>>>(
          out_w + (size_t)l * DD * DD, whi, nullptr, DD, DD);
      wh = whi;
    }
    k_mgemm<0,0,0,2><<<dim3(DD/128, TT/128, 2), 256, 0, stream>>>(
        ahi, alo, wh, nullptr, nullptr, t1, t3, nullptr, nullptr, DD, DD, 6);
    k_lnS<2,0,1><<<TT, 256, 0, stream>>>(t1, t3, nullptr, h, n1_g, n1_b,
        ff_g + (size_t)l*DD, ff_b + (size_t)l*DD, h, ahi, alo);
    // ---- ff1 (2-term) ----
    if (full) wh = f1h + (size_t)l * DD * MFF;
    else {
      k_wsplit<0><<<dim3(MFF/64, DD/64, 1), 256, 0, stream>>>(
          ff_w1 + (size_t)l * DD * MFF, whi, nullptr, DD, MFF);
      wh = whi;
    }
    k_mgemm<1,1,0,2><<<dim3(MFF/128, TT/128, 1), 256, 0, stream>>>(
        ahi, alo, wh, nullptr, ff_b1 + (size_t)l*MFF, nullptr, nullptr, bhi, blo, DD, MFF, 8);
    // ---- ff2 (2-term, split-K=2) ----
    if (full) wh = f2h + (size_t)l * MFF * DD;
    else {
      k_wsplit<0><<<dim3(DD/64, MFF/64, 1), 256, 0, stream>>>(
          ff_w2 + (size_t)l * MFF * DD, whi, nullptr, MFF, DD);
      wh = whi;
    }
    k_mgemm<0,0,0,2><<<dim3(DD/128, TT/128, 2), 256, 0, stream>>>(
        bhi, blo, wh, nullptr, nullptr, t1, t3, nullptr, nullptr, MFF, DD, 6);
    k_lnS<2,0,0><<<TT, 256, 0, stream>>>(t1, t3, ff_b2 + (size_t)l*DD, h,
        n2_g, n2_b, nullptr, nullptr, h, ahi, alo);
  }
  // ---- head: w1 (3-term, split-K=2), then bias+GELU+LN fused reducer ----
  {
    const unsigned short *wh, *wl;
    if (full) { wh = hw1h; wl = hw1l; }
    else {
      k_wsplit<1><<<dim3(DD/64, DD/64, 1), 256, 0, stream>>>(h_w1, whi, wlo, DD, DD);
      wh = whi; wl = wlo;
    }
    k_mgemm<0,0,0,3><<<dim3(DD/128, TT/128, 2), 256, 0, stream>>>(
        ahi, alo, wh, wl, nullptr, t1, t3, nullptr, nullptr, DD, DD, 6);
    k_lnS<2,1,0><<<TT, 256, 0, stream>>>(t1, t3, h_b1, nullptr, h_g, h_b,
        nullptr, nullptr, nullptr, ahi, alo);
    if (full) { wh = lgh; wl = lgl; }
    else {
      k_wsplit<1><<<dim3(VV/64, DD/64, 1), 256, 0, stream>>>(h_w2, whi, wlo, DD, VV);
      wh = whi; wl = wlo;
    }
    k_mgemm<0,0,1,3><<<dim3(VV/128, TT/128, 1), 256, 0, stream>>>(
        ahi, alo, wh, wl, h_b2, outp, nullptr, nullptr, nullptr, DD, VV, 10);
  }
  k_copyh0<<<(BB * DD + 255) / 256, 256, 0, stream>>>(h, outp + (size_t)TT * VV);
}

// Round 7
// 3665.985 us; speedup vs baseline: 4.1648x; 1.0400x over previous
//
#include <hip/hip_runtime.h>
#include <math.h>

#define DD 768
#define HH 12
#define DHH 64
#define NLAYER 12
#define MFF 3072
#define VV 32000
#define BB 8
#define NN 512
#define TT (BB*NN)

typedef __attribute__((ext_vector_type(8))) short bf16x8;
typedef __attribute__((ext_vector_type(4))) float f32x4;

// ---------- bf16 helpers (RTNE) ----------
__device__ __forceinline__ unsigned short f2bf(float x) {
  unsigned u = __float_as_uint(x);
  unsigned r = u + 0x7FFFu + ((u >> 16) & 1u);
  return (unsigned short)(r >> 16);
}
__device__ __forceinline__ float bf2f(unsigned short h) {
  return __uint_as_float(((unsigned)h) << 16);
}

// ---------- async global->LDS 16B ----------
__device__ __forceinline__ void gl16(const void* g, void* l) {
  __builtin_amdgcn_global_load_lds(
      (const __attribute__((address_space(1))) unsigned*)g,
      (__attribute__((address_space(3))) unsigned*)l, 16, 0, 0);
}

// ---------- block-wide sum reduction of two values (256 threads = 4 waves) ----------
__device__ __forceinline__ void blockReduce2(float& a, float& b, float* sh) {
#pragma unroll
  for (int off = 32; off > 0; off >>= 1) {
    a += __shfl_down(a, off, 64);
    b += __shfl_down(b, off, 64);
  }
  int lane = threadIdx.x & 63;
  int w = threadIdx.x >> 6;
  if (lane == 0) { sh[2*w] = a; sh[2*w+1] = b; }
  __syncthreads();
  a = sh[0] + sh[2] + sh[4] + sh[6];
  b = sh[1] + sh[3] + sh[5] + sh[7];
}

// ---------- rope cos/sin tables: [NN][16] ----------
__global__ void k_ropetab(float* __restrict__ rc, float* __restrict__ rsn) {
  int i = blockIdx.x * 256 + threadIdx.x;
  if (i < NN * 16) {
    int pos = i >> 4, pr = i & 15;
    float inv = expf(-0.57564627324851148f * (float)pr);  // 10000^(-pr/16)
    float ang = (float)pos * inv;
    rc[i] = cosf(ang); rsn[i] = sinf(ang);
  }
}

// ---------- embedding gather + sinusoid PE + LayerNorm (+ bf16 out) ----------
__global__ __launch_bounds__(256) void k_embed_ln(const float* __restrict__ emb,
    const float* __restrict__ g, const float* __restrict__ bb,
    const int* __restrict__ x, float* __restrict__ out,
    unsigned short* __restrict__ ob) {
  __shared__ float sh[8];
  int tok = blockIdx.x;
  int n = tok & (NN - 1);
  int t = x[tok];
  const float* row = emb + (size_t)t * DD;
  float v[3]; float s = 0.f, ss = 0.f;
#pragma unroll
  for (int i = 0; i < 3; ++i) {
    int d = threadIdx.x + 256 * i;
    int pair = d >> 1;
    float div = expf((float)(2 * pair) * (-9.210340371976184f / (float)DD));
    float ang = (float)n * div;
    float pe = (d & 1) ? cosf(ang) : sinf(ang);
    float val = row[d] + pe;
    v[i] = val; s += val; ss += val * val;
  }
  blockReduce2(s, ss, sh);
  float mu = s * (1.f / DD);
  float var = ss * (1.f / DD) - mu * mu;
  float rs = rsqrtf(var + 1e-5f);
#pragma unroll
  for (int i = 0; i < 3; ++i) {
    int d = threadIdx.x + 256 * i;
    float val = (v[i] - mu) * rs * g[d] + bb[d];
    size_t idx = (size_t)tok * DD + d;
    out[idx] = val;
    ob[idx] = f2bf(val);
  }
}

// ---------- fused reducer + LayerNorm(s), bf16 out ----------
template<int NP, int GELU, int LN2>
__global__ __launch_bounds__(256) void k_lnS(
    const float* __restrict__ p0, const float* __restrict__ p1,
    const float* __restrict__ bias, const float* __restrict__ res,
    const float* __restrict__ g1, const float* __restrict__ b1v,
    const float* __restrict__ g2, const float* __restrict__ b2v,
    float* __restrict__ outf, unsigned short* __restrict__ ob) {
  __shared__ float sh[8];
  int tok = blockIdx.x;
  float v[3]; float s = 0.f, ss = 0.f;
#pragma unroll
  for (int i = 0; i < 3; ++i) {
    int d = threadIdx.x + 256 * i;
    size_t idx = (size_t)tok * DD + d;
    float val = p0[idx];
    if (NP > 1) val += p1[idx];
    if (bias) val += bias[d];
    if (res) val += res[idx];
    if (GELU) val = 0.5f * val * (1.f + erff(val * 0.70710678118654752f));
    v[i] = val; s += val; ss += val * val;
  }
  blockReduce2(s, ss, sh);
  float mu = s * (1.f / DD);
  float var = ss * (1.f / DD) - mu * mu;
  float rs = rsqrtf(var + 1e-5f);
  if (LN2) {
    float y[3]; float s2 = 0.f, ss2 = 0.f;
#pragma unroll
    for (int i = 0; i < 3; ++i) {
      int d = threadIdx.x + 256 * i;
      float yy = (v[i] - mu) * rs * g1[d] + b1v[d];
      y[i] = yy; s2 += yy; ss2 += yy * yy;
      outf[(size_t)tok * DD + d] = yy;
    }
    __syncthreads();
    blockReduce2(s2, ss2, sh);
    float mu2 = s2 * (1.f / DD);
    float var2 = ss2 * (1.f / DD) - mu2 * mu2;
    float rs2 = rsqrtf(var2 + 1e-5f);
#pragma unroll
    for (int i = 0; i < 3; ++i) {
      int d = threadIdx.x + 256 * i;
      float val = (y[i] - mu2) * rs2 * g2[d] + b2v[d];
      ob[(size_t)tok * DD + d] = f2bf(val);
    }
  } else {
#pragma unroll
    for (int i = 0; i < 3; ++i) {
      int d = threadIdx.x + 256 * i;
      float val = (v[i] - mu) * rs * g1[d] + b1v[d];
      size_t idx = (size_t)tok * DD + d;
      if (outf) outf[idx] = val;
      ob[idx] = f2bf(val);
    }
  }
}

// ---------- RoPE on 8 packed bf16 (4 pairs) via table, base = pos*16 + pair0 ----------
__device__ __forceinline__ void rope8t(bf16x8& v, const float* __restrict__ rc,
    const float* __restrict__ rsn, int base) {
#pragma unroll
  for (int i = 0; i < 4; ++i) {
    float cs = rc[base + i];
    float sn = rsn[base + i];
    float x0 = bf2f((unsigned short)v[2*i]);
    float x1 = bf2f((unsigned short)v[2*i+1]);
    v[2*i]   = (short)f2bf(x0 * cs - x1 * sn);
    v[2*i+1] = (short)f2bf(x1 * cs + x0 * sn);
  }
}

// ---------- MFMA flash attention: block = 64 q rows of one (b,h), 4 waves x 16 rows ----------
__global__ __launch_bounds__(256) void k_attn(const unsigned short* __restrict__ qkvb,
    const int* __restrict__ x, const float* __restrict__ rc, const float* __restrict__ rsn,
    unsigned short* __restrict__ ob) {
  __shared__ unsigned short Ks[64][72];
  __shared__ unsigned short Vt[64][72];
  __shared__ unsigned short Ps[4][16][72];
  __shared__ float maskv[64];
  int nblk = gridDim.x;
  int bid = blockIdx.x;
  int blk = (bid & 7) * (nblk >> 3) + (bid >> 3);
  int qb = blk & 7;
  int hh = (blk >> 3) % HH;
  int b = blk / (8 * HH);
  int q0 = qb * 64;
  int tid = threadIdx.x;
  int w = tid >> 6, l = tid & 63;
  int g = l >> 4, c = l & 15;

  bf16x8 qa0, qa1;
  {
    int q = q0 + 16 * w + c;
    const unsigned short* qp = qkvb + (size_t)(b * NN + q) * (3 * DD) + hh * DHH;
    qa0 = *(const bf16x8*)(qp + 8 * g);
    qa1 = *(const bf16x8*)(qp + 32 + 8 * g);
    rope8t(qa0, rc, rsn, q * 16 + 4 * g);
  }
  f32x4 o[4];
#pragma unroll
  for (int f = 0; f < 4; ++f) o[f] = (f32x4){0.f,0.f,0.f,0.f};
  float m_run[4] = {-INFINITY,-INFINITY,-INFINITY,-INFINITY};
  float l_run[4] = {0.f,0.f,0.f,0.f};

  int kr = tid >> 2;
  int kd = (tid & 3) * 16;
  for (int kt = 0; kt < NN; kt += 64) {
    __syncthreads();
    {
      int tok = b * NN + kt + kr;
      const unsigned short* kp = qkvb + (size_t)tok * (3 * DD) + DD + hh * DHH + kd;
      const unsigned short* vp = kp + DD;
      bf16x8 k0 = *(const bf16x8*)kp;
      bf16x8 k1 = *(const bf16x8*)(kp + 8);
      if (kd < 32) {
        int base = (kt + kr) * 16 + kd / 2;
        rope8t(k0, rc, rsn, base);
        rope8t(k1, rc, rsn, base + 4);
      }
      *(bf16x8*)&Ks[kr][kd] = k0;
      *(bf16x8*)&Ks[kr][kd + 8] = k1;
      bf16x8 v0 = *(const bf16x8*)vp;
      bf16x8 v1 = *(const bf16x8*)(vp + 8);
#pragma unroll
      for (int j = 0; j < 8; ++j) {
        Vt[kd + j][kr] = (unsigned short)v0[j];
        Vt[kd + 8 + j][kr] = (unsigned short)v1[j];
      }
    }
    if (tid < 64) maskv[tid] = (x[b * NN + kt + tid] == 0) ? 1.f : 0.f;
    __syncthreads();

    f32x4 sc[4];
#pragma unroll
    for (int f = 0; f < 4; ++f) {
      bf16x8 kb0 = *(const bf16x8*)&Ks[16 * f + c][8 * g];
      bf16x8 kb1 = *(const bf16x8*)&Ks[16 * f + c][32 + 8 * g];
      f32x4 sacc = (f32x4){0.f,0.f,0.f,0.f};
      sacc = __builtin_amdgcn_mfma_f32_16x16x32_bf16(qa0, kb0, sacc, 0, 0, 0);
      sacc = __builtin_amdgcn_mfma_f32_16x16x32_bf16(qa1, kb1, sacc, 0, 0, 0);
      float mk = maskv[16 * f + c];
#pragma unroll
      for (int r = 0; r < 4; ++r) {
        float sv = sacc[r] * 0.125f;
        sacc[r] = (mk != 0.f) ? 1e-9f : sv;
      }
      sc[f] = sacc;
    }
    float fs[4];
#pragma unroll
    for (int r = 0; r < 4; ++r) {
      float m = fmaxf(fmaxf(sc[0][r], sc[1][r]), fmaxf(sc[2][r], sc[3][r]));
      m = fmaxf(m, __shfl_xor(m, 1, 64));
      m = fmaxf(m, __shfl_xor(m, 2, 64));
      m = fmaxf(m, __shfl_xor(m, 4, 64));
      m = fmaxf(m, __shfl_xor(m, 8, 64));
      float mn = fmaxf(m_run[r], m);
      fs[r] = expf(m_run[r] - mn);
      m_run[r] = mn;
    }
    float tsum[4] = {0.f,0.f,0.f,0.f};
#pragma unroll
    for (int f = 0; f < 4; ++f)
#pragma unroll
      for (int r = 0; r < 4; ++r) {
        float p = expf(sc[f][r] - m_run[r]);
        Ps[w][4 * g + r][16 * f + c] = f2bf(p);
        tsum[r] += p;
      }
#pragma unroll
    for (int r = 0; r < 4; ++r) {
      float t = tsum[r];
      t += __shfl_xor(t, 1, 64);
      t += __shfl_xor(t, 2, 64);
      t += __shfl_xor(t, 4, 64);
      t += __shfl_xor(t, 8, 64);
      l_run[r] = l_run[r] * fs[r] + t;
#pragma unroll
      for (int f = 0; f < 4; ++f) o[f][r] *= fs[r];
    }
    asm volatile("s_waitcnt lgkmcnt(0)" ::: "memory");
    __builtin_amdgcn_sched_barrier(0);
    bf16x8 pa0 = *(const bf16x8*)&Ps[w][c][8 * g];
    bf16x8 pa1 = *(const bf16x8*)&Ps[w][c][32 + 8 * g];
#pragma unroll
    for (int f = 0; f < 4; ++f) {
      bf16x8 vb0 = *(const bf16x8*)&Vt[16 * f + c][8 * g];
      bf16x8 vb1 = *(const bf16x8*)&Vt[16 * f + c][32 + 8 * g];
      o[f] = __builtin_amdgcn_mfma_f32_16x16x32_bf16(pa0, vb0, o[f], 0, 0, 0);
      o[f] = __builtin_amdgcn_mfma_f32_16x16x32_bf16(pa1, vb1, o[f], 0, 0, 0);
    }
  }
#pragma unroll
  for (int r = 0; r < 4; ++r) {
    int tok = b * NN + q0 + 16 * w + 4 * g + r;
    float invl = 1.f / l_run[r];
#pragma unroll
    for (int f = 0; f < 4; ++f) {
      float vv = o[f][r] * invl;
      ob[(size_t)tok * DD + hh * DHH + 16 * f + c] = f2bf(vv);
    }
  }
}

// ---------- weight transpose + bf16 hi/lo split: W[z][K][N] -> Wt{hi,lo}[z][N][K] ----------
__global__ __launch_bounds__(256) void k_wsplit(const float* __restrict__ W,
    unsigned short* __restrict__ Whi, unsigned short* __restrict__ Wlo, int K, int N) {
  __shared__ float tile[64][65];
  size_t zoff = (size_t)blockIdx.z * K * N;
  W += zoff; Whi += zoff; Wlo += zoff;
  int k0 = blockIdx.y * 64, n0 = blockIdx.x * 64;
  int tid = threadIdx.x;
#pragma unroll
  for (int it = 0; it < 4; ++it) {
    int r = (tid >> 4) + it * 16;
    int c = (tid & 15) * 4;
    float4 v = *(const float4*)&W[(size_t)(k0 + r) * N + n0 + c];
    tile[r][c] = v.x; tile[r][c+1] = v.y; tile[r][c+2] = v.z; tile[r][c+3] = v.w;
  }
  __syncthreads();
  int n = tid >> 2;
  int kb = (tid & 3) * 16;
  bf16x8 h0, h1, l0, l1;
#pragma unroll
  for (int i = 0; i < 8; ++i) {
    float xv = tile[kb + i][n];
    unsigned short h = f2bf(xv);
    h0[i] = (short)h; l0[i] = (short)f2bf(xv - bf2f(h));
  }
#pragma unroll
  for (int i = 0; i < 8; ++i) {
    float xv = tile[kb + 8 + i][n];
    unsigned short h = f2bf(xv);
    h1[i] = (short)h; l1[i] = (short)f2bf(xv - bf2f(h));
  }
  size_t ob = (size_t)(n0 + n) * K + k0 + kb;
  *(bf16x8*)&Whi[ob] = h0; *(bf16x8*)&Whi[ob + 8] = h1;
  *(bf16x8*)&Wlo[ob] = l0; *(bf16x8*)&Wlo[ob + 8] = l1;
}

// ---------- 2-term MFMA GEMM: C[T x Nc] = A_bf16 @ (Whi + Wlo) ----------
// SPLIT: 0 = fp32 out (Cz), 2 = bf16 out (Chi). NT: nontemporal fp32 store.
// grid.z = deterministic split-K chunks: z=0 -> C, z=1 -> C1.
// Block remap: XCD-bijective swizzle + N-chunks of CHX panels (bx fast within chunk).
template<int ACT, int SPLIT, int NT>
__global__ __launch_bounds__(256) void k_mgemm(
    const unsigned short* __restrict__ Ab,
    const unsigned short* __restrict__ Whi, const unsigned short* __restrict__ Wlo,
    const float* __restrict__ bias, float* __restrict__ C, float* __restrict__ C1,
    unsigned short* __restrict__ Chi,
    int K, int Nc, int CHX) {
  __shared__ unsigned short As[128*32], BsH[128*32], BsL[128*32];
  int nbx = gridDim.x, nby = gridDim.y;
  int bid = blockIdx.y * nbx + blockIdx.x;
  int nwg = nbx * nby;
  int sw = (bid & 7) * (nwg >> 3) + (bid >> 3);
  int per = CHX * nby;
  int st = sw / per, off = sw - st * per;
  int bx = st * CHX + (off % CHX);
  int by = off / CHX;
  int brow = by * 128, bcol = bx * 128;
  int Kc = K / gridDim.z;
  int kbeg = blockIdx.z * Kc;
  float* Cz = (blockIdx.z == 0) ? C : C1;
  int tid = threadIdx.x;
  int w = tid >> 6, l = tid & 63;
  int wr = w >> 1, wc = w & 1;
  int lr = l & 15;
  int lk = l >> 4;
  int srow = w * 16 + (l >> 2);
  int skc = (l & 3) * 8;
  const unsigned short* pA  = Ab  + (size_t)(brow + srow) * K + kbeg + skc;
  const unsigned short* pBh = Whi + (size_t)(bcol + srow) * K + kbeg + skc;
  const unsigned short* pBl = Wlo + (size_t)(bcol + srow) * K + kbeg + skc;
  size_t half = (size_t)64 * K;
  f32x4 acc[4][4];
#pragma unroll
  for (int i = 0; i < 4; ++i)
#pragma unroll
    for (int j = 0; j < 4; ++j) acc[i][j] = (f32x4){0.f, 0.f, 0.f, 0.f};
  int sAo = srow * 32 + skc;
  for (int k0 = 0; k0 < Kc; k0 += 32) {
    __syncthreads();
    gl16(pA,  &As[sAo]);  gl16(pA + half,  &As[sAo + 64*32]);
    gl16(pBh, &BsH[sAo]); gl16(pBh + half, &BsH[sAo + 64*32]);
    gl16(pBl, &BsL[sAo]); gl16(pBl + half, &BsL[sAo + 64*32]);
    pA += 32; pBh += 32; pBl += 32;
    __syncthreads();
    bf16x8 a[4], bh[4], bl[4];
#pragma unroll
    for (int i = 0; i < 4; ++i) {
      int ar = (wr*64 + i*16 + lr) * 32 + lk*8;
      int br = (wc*64 + i*16 + lr) * 32 + lk*8;
      a[i]  = *(const bf16x8*)&As[ar];
      bh[i] = *(const bf16x8*)&BsH[br];
      bl[i] = *(const bf16x8*)&BsL[br];
    }
#pragma unroll
    for (int mi = 0; mi < 4; ++mi)
#pragma unroll
      for (int ni = 0; ni < 4; ++ni) {
        acc[mi][ni] = __builtin_amdgcn_mfma_f32_16x16x32_bf16(a[mi], bh[ni], acc[mi][ni], 0, 0, 0);
        acc[mi][ni] = __builtin_amdgcn_mfma_f32_16x16x32_bf16(a[mi], bl[ni], acc[mi][ni], 0, 0, 0);
      }
  }
#pragma unroll
  for (int mi = 0; mi < 4; ++mi) {
    int row0 = brow + wr*64 + mi*16 + lk*4;
#pragma unroll
    for (int ni = 0; ni < 4; ++ni) {
      int col = bcol + wc*64 + ni*16 + lr;
      float bv = bias ? bias[col] : 0.f;
#pragma unroll
      for (int r = 0; r < 4; ++r) {
        float v = acc[mi][ni][r] + bv;
        if (ACT == 1) v = 0.5f * v * (1.f + erff(v * 0.70710678118654752f));
        size_t idx = (size_t)(row0 + r) * Nc + col;
        if (SPLIT == 2) {
          Chi[idx] = f2bf(v);
        } else {
          if (NT) __builtin_nontemporal_store(v, &Cz[idx]);
          else Cz[idx] = v;
        }
      }
    }
  }
}

// ---------- copy h[:,0,:] to second output ----------
__global__ void k_copyh0(const float* __restrict__ h, float* __restrict__ o2) {
  int i = blockIdx.x * 256 + threadIdx.x;
  if (i < BB * DD) {
    int b = i / DD, d = i - b * DD;
    o2[i] = h[(size_t)(b * NN) * DD + d];
  }
}

extern "C" void kernel_launch(void* const* d_in, const int* in_sizes, int n_in,
                              void* d_out, int out_size, void* d_ws, size_t ws_size,
                              hipStream_t stream) {
  const float* tok_emb = (const float*)d_in[0];
  const float* emb_g  = (const float*)d_in[1];
  const float* emb_b  = (const float*)d_in[2];
  const float* n1_g   = (const float*)d_in[3];
  const float* n1_b   = (const float*)d_in[4];
  const float* n2_g   = (const float*)d_in[5];
  const float* n2_b   = (const float*)d_in[6];
  const float* qkv_w  = (const float*)d_in[7];
  const float* out_w  = (const float*)d_in[8];
  const float* ff_g   = (const float*)d_in[9];
  const float* ff_b   = (const float*)d_in[10];
  const float* ff_w1  = (const float*)d_in[11];
  const float* ff_b1  = (const float*)d_in[12];
  const float* ff_w2  = (const float*)d_in[13];
  const float* ff_b2  = (const float*)d_in[14];
  const float* h_w1   = (const float*)d_in[15];
  const float* h_b1   = (const float*)d_in[16];
  const float* h_g    = (const float*)d_in[17];
  const float* h_b    = (const float*)d_in[18];
  const float* h_w2   = (const float*)d_in[19];
  const float* h_b2   = (const float*)d_in[20];
  const int*   xi     = (const int*)d_in[21];
  float* outp = (float*)d_out;

  size_t szH  = (size_t)TT * DD;          // floats
  size_t szAB = (size_t)TT * DD;          // ushorts (ln/attn bf16 act)
  size_t szBB = (size_t)TT * MFF;         // ushorts (ff1 bf16 act)
  size_t szQ  = (size_t)TT * 3 * DD;      // ushorts (qkv bf16)
  size_t szW  = (size_t)DD * VV;          // ushorts per shared split weight buffer
  size_t szRT = (size_t)NN * 16;          // floats per rope table

  size_t eQKV = (size_t)NLAYER * DD * 3 * DD;
  size_t eOUT = (size_t)NLAYER * DD * DD;
  size_t eFF1 = (size_t)NLAYER * DD * MFF;
  size_t eFF2 = (size_t)NLAYER * MFF * DD;
  size_t eHW1 = (size_t)DD * DD;
  size_t eLG  = (size_t)DD * VV;
  size_t eWT  = eQKV + eOUT + eFF1 + eFF2 + eHW1 + eLG;

  size_t actBytes = szH*4*3 + szQ*2 + szAB*2 + szBB*2 + szRT*4*2;
  size_t needFull = actBytes + eWT * 2 * 2;   // hi+lo, 2B each

  char* p = (char*)d_ws;
  float* h   = (float*)p;                   p += szH * 4;
  float* t1  = (float*)p;                   p += szH * 4;
  float* t3  = (float*)p;                   p += szH * 4;
  unsigned short* t1b = (unsigned short*)p; p += szQ * 2;
  unsigned short* ab  = (unsigned short*)p; p += szAB * 2;   // DD-wide bf16 act
  unsigned short* fb  = (unsigned short*)p; p += szBB * 2;   // MFF-wide bf16 act
  float* ropc = (float*)p;                  p += szRT * 4;
  float* rops = (float*)p;                  p += szRT * 4;

  bool full = (ws_size >= needFull);
  unsigned short *qkvh, *qkvl, *outh, *outl, *f1h, *f1l, *f2h, *f2l, *hw1h, *hw1l, *lgh, *lgl;
  unsigned short *whi = nullptr, *wlo = nullptr;
  if (full) {
    qkvh = (unsigned short*)p; p += eQKV * 2; qkvl = (unsigned short*)p; p += eQKV * 2;
    outh = (unsigned short*)p; p += eOUT * 2; outl = (unsigned short*)p; p += eOUT * 2;
    f1h  = (unsigned short*)p; p += eFF1 * 2; f1l  = (unsigned short*)p; p += eFF1 * 2;
    f2h  = (unsigned short*)p; p += eFF2 * 2; f2l  = (unsigned short*)p; p += eFF2 * 2;
    hw1h = (unsigned short*)p; p += eHW1 * 2; hw1l = (unsigned short*)p; p += eHW1 * 2;
    lgh  = (unsigned short*)p; p += eLG * 2;  lgl  = (unsigned short*)p;
    k_wsplit<<<dim3(3*DD/64, DD/64, NLAYER), 256, 0, stream>>>(qkv_w, qkvh, qkvl, DD, 3*DD);
    k_wsplit<<<dim3(DD/64, DD/64, NLAYER), 256, 0, stream>>>(out_w, outh, outl, DD, DD);
    k_wsplit<<<dim3(MFF/64, DD/64, NLAYER), 256, 0, stream>>>(ff_w1, f1h, f1l, DD, MFF);
    k_wsplit<<<dim3(DD/64, MFF/64, NLAYER), 256, 0, stream>>>(ff_w2, f2h, f2l, MFF, DD);
    k_wsplit<<<dim3(DD/64, DD/64, 1), 256, 0, stream>>>(h_w1, hw1h, hw1l, DD, DD);
    k_wsplit<<<dim3(VV/64, DD/64, 1), 256, 0, stream>>>(h_w2, lgh, lgl, DD, VV);
  } else {
    whi = (unsigned short*)p; p += szW * 2;
    wlo = (unsigned short*)p;
  }

  k_ropetab<<<(NN*16 + 255)/256, 256, 0, stream>>>(ropc, rops);
  k_embed_ln<<<TT, 256, 0, stream>>>(tok_emb, emb_g, emb_b, xi, h, ab);
  for (int l = 0; l < NLAYER; ++l) {
    const unsigned short *wh, *wl;
    // ---- qkv ----
    if (full) { wh = qkvh + (size_t)l * DD * 3 * DD; wl = qkvl + (size_t)l * DD * 3 * DD; }
    else {
      k_wsplit<<<dim3(3*DD/64, DD/64, 1), 256, 0, stream>>>(
          qkv_w + (size_t)l * DD * 3 * DD, whi, wlo, DD, 3*DD);
      wh = whi; wl = wlo;
    }
    k_mgemm<0,2,0><<<dim3(3*DD/128, TT/128, 1), 256, 0, stream>>>(
        ab, wh, wl, nullptr, nullptr, nullptr, t1b, DD, 3*DD, 6);
    k_attn<<<BB * HH * (NN/64), 256, 0, stream>>>(t1b, xi, ropc, rops, ab);
    // ---- attn out (split-K=2 -> t1,t3; reduce+2xLN fused) ----
    if (full) { wh = outh + (size_t)l * DD * DD; wl = outl + (size_t)l * DD * DD; }
    else {
      k_wsplit<<<dim3(DD/64, DD/64, 1), 256, 0, stream>>>(
          out_w + (size_t)l * DD * DD, whi, wlo, DD, DD);
      wh = whi; wl = wlo;
    }
    k_mgemm<0,0,0><<<dim3(DD/128, TT/128, 2), 256, 0, stream>>>(
        ab, wh, wl, nullptr, t1, t3, nullptr, DD, DD, 6);
    k_lnS<2,0,1><<<TT, 256, 0, stream>>>(t1, t3, nullptr, h, n1_g, n1_b,
        ff_g + (size_t)l*DD, ff_b + (size_t)l*DD, h, ab);
    // ---- ff1 ----
    if (full) { wh = f1h + (size_t)l * DD * MFF; wl = f1l + (size_t)l * DD * MFF; }
    else {
      k_wsplit<<<dim3(MFF/64, DD/64, 1), 256, 0, stream>>>(
          ff_w1 + (size_t)l * DD * MFF, whi, wlo, DD, MFF);
      wh = whi; wl = wlo;
    }
    k_mgemm<1,2,0><<<dim3(MFF/128, TT/128, 1), 256, 0, stream>>>(
        ab, wh, wl, ff_b1 + (size_t)l*MFF, nullptr, nullptr, fb, DD, MFF, 8);
    // ---- ff2 (split-K=2) ----
    if (full) { wh = f2h + (size_t)l * MFF * DD; wl = f2l + (size_t)l * MFF * DD; }
    else {
      k_wsplit<<<dim3(DD/64, MFF/64, 1), 256, 0, stream>>>(
          ff_w2 + (size_t)l * MFF * DD, whi, wlo, MFF, DD);
      wh = whi; wl = wlo;
    }
    k_mgemm<0,0,0><<<dim3(DD/128, TT/128, 2), 256, 0, stream>>>(
        fb, wh, wl, nullptr, t1, t3, nullptr, MFF, DD, 6);
    k_lnS<2,0,0><<<TT, 256, 0, stream>>>(t1, t3, ff_b2 + (size_t)l*DD, h,
        n2_g, n2_b, nullptr, nullptr, h, ab);
  }
  // ---- head: w1 (split-K=2), then bias+GELU+LN fused reducer ----
  {
    const unsigned short *wh, *wl;
    if (full) { wh = hw1h; wl = hw1l; }
    else {
      k_wsplit<<<dim3(DD/64, DD/64, 1), 256, 0, stream>>>(h_w1, whi, wlo, DD, DD);
      wh = whi; wl = wlo;
    }
    k_mgemm<0,0,0><<<dim3(DD/128, TT/128, 2), 256, 0, stream>>>(
        ab, wh, wl, nullptr, t1, t3, nullptr, DD, DD, 6);
    k_lnS<2,1,0><<<TT, 256, 0, stream>>>(t1, t3, h_b1, nullptr, h_g, h_b,
        nullptr, nullptr, nullptr, ab);
    if (full) { wh = lgh; wl = lgl; }
    else {
      k_wsplit<<<dim3(VV/64, DD/64, 1), 256, 0, stream>>>(h_w2, whi, wlo, DD, VV);
      wh = whi; wl = wlo;
    }
    k_mgemm<0,0,1><<<dim3(VV/128, TT/128, 1), 256, 0, stream>>>(
        ab, wh, wl, h_b2, outp, nullptr, nullptr, DD, VV, 10);
  }
  k_copyh0<<<(BB * DD + 255) / 256, 256, 0, stream>>>(h, outp + (size_t)TT * VV);
}